// Round 13
// baseline (26778.336 us; speedup 1.0000x reference)
//
#include <hip/hip_runtime.h>
#include <cmath>
#include <cstddef>

// S=T=64, B=32, H=1024, G=4H, V=32000
constexpr int S_ = 64, T_ = 64, B_ = 32, H_ = 1024, G_ = 4096, V_ = 32000;
constexpr int NB = 256, BT = 512, NTHR = NB * BT, NWAVE = NB * 8;

typedef unsigned short u16;   // bf16 bit pattern
typedef __attribute__((ext_vector_type(8))) short bf16x8;
typedef __attribute__((ext_vector_type(4))) float f32x4;

__device__ __forceinline__ float sigf(float x) { return 1.f / (1.f + expf(-x)); }
__device__ __forceinline__ float b2f(u16 u) { return __uint_as_float(((unsigned)u) << 16); }
__device__ __forceinline__ u16 f2b(float f) {
  unsigned u = __float_as_uint(f);
  return (u16)((u + 0x7fff + ((u >> 16) & 1)) >> 16);  // RNE
}
__device__ __forceinline__ f32x4 mfma16(bf16x8 a, bf16x8 b, f32x4 c) {
  return __builtin_amdgcn_mfma_f32_16x16x32_bf16(a, b, c, 0, 0, 0);
}

struct Params {
  const int *input, *target, *use_tf;
  const float *enc_emb, *enc_Wih, *enc_Whh, *enc_b;
  const float *dec_emb, *dec_Wih, *dec_Whh, *dec_b;
  const float *attn_W, *attn_b, *comb_W, *comb_b, *out_W, *out_b;
  float* out;
  u16 *Xbf, *encXbf, *enc_bs, *hall, *hbuf, *xb, *vb, *nbuf, *xball, *ring;
  float *combX, *scoreX, *gatesH, *cbuf, *loss_p;
  int* prevtok;
  u16 *wencWih, *wencWhh, *wdecG, *wcomb, *wattn, *wout;
  unsigned* bar;   // [0..255] group counters (16 spaced 16) | [256] root | [512+g*16] release lines
};

// ---------- two-level grid barrier, fan-out release (16 lines), tight spin ----------
__device__ __forceinline__ void gbar(unsigned* bar, unsigned target) {
  __syncthreads();
  if (threadIdx.x == 0) {
    __threadfence();
    int g = blockIdx.x >> 4;
    unsigned a = __hip_atomic_fetch_add(bar + g * 16, 1u, __ATOMIC_ACQ_REL,
                                        __HIP_MEMORY_SCOPE_AGENT);
    if (a == 15u) {
      unsigned r = __hip_atomic_fetch_add(bar + 256, 1u, __ATOMIC_ACQ_REL,
                                          __HIP_MEMORY_SCOPE_AGENT);
      if (r == 15u) {
        for (int i = 0; i < 16; ++i)
          __hip_atomic_store(bar + i * 16, 0u, __ATOMIC_RELAXED, __HIP_MEMORY_SCOPE_AGENT);
        __hip_atomic_store(bar + 256, 0u, __ATOMIC_RELAXED, __HIP_MEMORY_SCOPE_AGENT);
#pragma unroll
        for (int i = 0; i < 16; ++i)
          __hip_atomic_store(bar + 512 + i * 16, target, __ATOMIC_RELEASE,
                             __HIP_MEMORY_SCOPE_AGENT);
      }
    }
    while (__hip_atomic_load(bar + 512 + g * 16, __ATOMIC_ACQUIRE,
                             __HIP_MEMORY_SCOPE_AGENT) < target) {}
  }
  __syncthreads();
}

// ---------- per-wave 32x64 tile GEMM, K=1024 ----------
// EPI: 0 bf16, 1 bf16+bias, 2 f32, 3 f32+bias
template <int EPI>
__device__ void wave_gemm(const u16* __restrict__ A, const u16* __restrict__ W,
                          int ldw, int wkoff, int colbase, const float* __restrict__ bias,
                          void* __restrict__ outp, int ldo) {
  const int lane = threadIdx.x & 63;
  const int r = lane & 15, kg = (lane >> 4) * 8;
  const u16* Ar = A + (size_t)r * 1024 + kg;
  const u16* Wr = W + (size_t)(colbase + r) * ldw + wkoff + kg;
  f32x4 acc[2][4] = {};
#pragma unroll 2
  for (int k0 = 0; k0 < 1024; k0 += 32) {
    bf16x8 a0 = *(const bf16x8*)(Ar + k0);
    bf16x8 a1 = *(const bf16x8*)(Ar + 16 * 1024 + k0);
    bf16x8 b0 = *(const bf16x8*)(Wr + k0);
    bf16x8 b1 = *(const bf16x8*)(Wr + (size_t)16 * ldw + k0);
    bf16x8 b2 = *(const bf16x8*)(Wr + (size_t)32 * ldw + k0);
    bf16x8 b3 = *(const bf16x8*)(Wr + (size_t)48 * ldw + k0);
    acc[0][0] = mfma16(a0, b0, acc[0][0]);
    acc[1][0] = mfma16(a1, b0, acc[1][0]);
    acc[0][1] = mfma16(a0, b1, acc[0][1]);
    acc[1][1] = mfma16(a1, b1, acc[1][1]);
    acc[0][2] = mfma16(a0, b2, acc[0][2]);
    acc[1][2] = mfma16(a1, b2, acc[1][2]);
    acc[0][3] = mfma16(a0, b3, acc[0][3]);
    acc[1][3] = mfma16(a1, b3, acc[1][3]);
  }
#pragma unroll
  for (int mi = 0; mi < 2; ++mi)
#pragma unroll
    for (int nj = 0; nj < 4; ++nj) {
      int col = colbase + nj * 16 + (lane & 15);
      int row0 = mi * 16 + ((lane >> 4) << 2);
#pragma unroll
      for (int reg = 0; reg < 4; ++reg) {
        float v = acc[mi][nj][reg];
        if (EPI == 1 || EPI == 3) v += bias[col];
        if (EPI <= 1) ((u16*)outp)[(size_t)(row0 + reg) * ldo + col] = f2b(v);
        else ((float*)outp)[(size_t)(row0 + reg) * ldo + col] = v;
      }
    }
}

// ---------- streamed block 32x64 grouped-col GEMM (tf=0 path) ----------
__device__ void grouped_gemm8(const u16* __restrict__ A, const u16* __restrict__ Wm,
                              int ldw, int wkoff, int grp, float* red, float* sg) {
  const int tid = threadIdx.x, w = tid >> 6, lane = tid & 63;
  const int r = lane & 15, kg = (lane >> 4) * 8;
  const int kw0 = w * 128;
  const u16* Ar = A + (size_t)r * 1024 + kw0 + kg;
  const u16* W0 = Wm + (size_t)(grp * 16 + r) * ldw + wkoff + kw0 + kg;
  const u16* W1 = W0 + (size_t)1024 * ldw;
  const u16* W2 = W0 + (size_t)2048 * ldw;
  const u16* W3 = W0 + (size_t)3072 * ldw;
  f32x4 acc[2][4] = {};
#pragma unroll
  for (int k0 = 0; k0 < 128; k0 += 32) {
    bf16x8 a0 = *(const bf16x8*)(Ar + k0);
    bf16x8 a1 = *(const bf16x8*)(Ar + 16 * 1024 + k0);
    bf16x8 b0 = *(const bf16x8*)(W0 + k0);
    bf16x8 b1 = *(const bf16x8*)(W1 + k0);
    bf16x8 b2 = *(const bf16x8*)(W2 + k0);
    bf16x8 b3 = *(const bf16x8*)(W3 + k0);
    acc[0][0] = mfma16(a0, b0, acc[0][0]);
    acc[1][0] = mfma16(a1, b0, acc[1][0]);
    acc[0][1] = mfma16(a0, b1, acc[0][1]);
    acc[1][1] = mfma16(a1, b1, acc[1][1]);
    acc[0][2] = mfma16(a0, b2, acc[0][2]);
    acc[1][2] = mfma16(a1, b2, acc[1][2]);
    acc[0][3] = mfma16(a0, b3, acc[0][3]);
    acc[1][3] = mfma16(a1, b3, acc[1][3]);
  }
#pragma unroll
  for (int mi = 0; mi < 2; ++mi)
#pragma unroll
    for (int nj = 0; nj < 4; ++nj)
#pragma unroll
      for (int reg = 0; reg < 4; ++reg)
        red[(((w * 8) + mi * 4 + nj) * 64 + lane) * 4 + reg] = acc[mi][nj][reg];
  __syncthreads();
  {
    const int p2 = w;
    const int mi = p2 >> 2, nj = p2 & 3;
#pragma unroll
    for (int reg = 0; reg < 4; ++reg) {
      float v = 0.f;
#pragma unroll
      for (int ww = 0; ww < 8; ++ww)
        v += red[(((ww * 8) + p2) * 64 + lane) * 4 + reg];
      sg[(mi * 16 + ((lane >> 4) << 2) + reg) * 64 + nj * 16 + (lane & 15)] = v;
    }
  }
  __syncthreads();
}

// ---------- pinned-weight loaders ----------
__device__ __forceinline__ void load_wpin_gates(const u16* Wm, int ldw, int wkoff,
                                                int grp, bf16x8* wp) {
  const int w = threadIdx.x >> 6, lane = threadIdx.x & 63;
  const int r = lane & 15, kg = (lane >> 4) * 8;
  const int kw0 = w * 128;
  const u16* W0 = Wm + (size_t)(grp * 16 + r) * ldw + wkoff + kw0 + kg;
#pragma unroll
  for (int q = 0; q < 4; ++q)
#pragma unroll
    for (int ks = 0; ks < 4; ++ks)
      wp[q * 4 + ks] = *(const bf16x8*)(W0 + (size_t)(q * 1024) * ldw + ks * 32);
}

__device__ __forceinline__ void load_wpin_comb(const u16* Wm, int cb, bf16x8* wp) {
  const int w = threadIdx.x >> 6, lane = threadIdx.x & 63;
  const int r = lane & 15, kg = (lane >> 4) * 8;
  const int kw0 = w * 128;
  const u16* W0 = Wm + (size_t)(cb * 32 + r) * 2048 + 1024 + kw0 + kg;
#pragma unroll
  for (int h = 0; h < 2; ++h)
#pragma unroll
    for (int ks = 0; ks < 4; ++ks)
      wp[h * 4 + ks] = *(const bf16x8*)(W0 + (size_t)(h * 16) * 2048 + ks * 32);
}

// ---------- pinned grouped-col GEMM -> sg[32][64] ----------
__device__ void grouped_gemm8_pinned(const u16* __restrict__ A, const bf16x8* wp,
                                     float* red, float* sg) {
  const int tid = threadIdx.x, w = tid >> 6, lane = tid & 63;
  const int r = lane & 15, kg = (lane >> 4) * 8;
  const int kw0 = w * 128;
  const u16* Ar = A + (size_t)r * 1024 + kw0 + kg;
  f32x4 acc[2][4] = {};
#pragma unroll
  for (int ks = 0; ks < 4; ++ks) {
    bf16x8 a0 = *(const bf16x8*)(Ar + ks * 32);
    bf16x8 a1 = *(const bf16x8*)(Ar + 16 * 1024 + ks * 32);
    acc[0][0] = mfma16(a0, wp[0 + ks], acc[0][0]);
    acc[1][0] = mfma16(a1, wp[0 + ks], acc[1][0]);
    acc[0][1] = mfma16(a0, wp[4 + ks], acc[0][1]);
    acc[1][1] = mfma16(a1, wp[4 + ks], acc[1][1]);
    acc[0][2] = mfma16(a0, wp[8 + ks], acc[0][2]);
    acc[1][2] = mfma16(a1, wp[8 + ks], acc[1][2]);
    acc[0][3] = mfma16(a0, wp[12 + ks], acc[0][3]);
    acc[1][3] = mfma16(a1, wp[12 + ks], acc[1][3]);
  }
#pragma unroll
  for (int mi = 0; mi < 2; ++mi)
#pragma unroll
    for (int nj = 0; nj < 4; ++nj)
#pragma unroll
      for (int reg = 0; reg < 4; ++reg)
        red[(((w * 8) + mi * 4 + nj) * 64 + lane) * 4 + reg] = acc[mi][nj][reg];
  __syncthreads();
  {
    const int p2 = w;
    const int mi = p2 >> 2, nj = p2 & 3;
#pragma unroll
    for (int reg = 0; reg < 4; ++reg) {
      float v = 0.f;
#pragma unroll
      for (int ww = 0; ww < 8; ++ww)
        v += red[(((ww * 8) + p2) * 64 + lane) * 4 + reg];
      sg[(mi * 16 + ((lane >> 4) << 2) + reg) * 64 + nj * 16 + (lane & 15)] = v;
    }
  }
  __syncthreads();
}

// ---------- streamed comb (tf=0): K=2048 over [xb|vb] ----------
template <int KTOT, bool HASX>
__device__ void comb8(const Params& p, int cb, int t, float* red) {
  const int tid = threadIdx.x, w = tid >> 6, lane = tid & 63;
  const int r = lane & 15, kg = (lane >> 4) * 8;
  constexpr int KSW = KTOT / 8;
  const int kw0 = w * KSW;
  const u16* Abase;
  int koff;
  if (KTOT == 2048) { Abase = (kw0 < 1024) ? p.xb : p.vb; koff = kw0 & 1023; }
  else { Abase = p.vb; koff = kw0; }
  const u16* Ar = Abase + (size_t)r * 1024 + koff + kg;
  const int wko = (KTOT == 1024) ? 1024 : 0;
  const u16* W0 = p.wcomb + (size_t)(cb * 32 + r) * 2048 + wko + kw0 + kg;
  const u16* W1 = W0 + (size_t)16 * 2048;
  f32x4 acc[2][2] = {};
#pragma unroll
  for (int k0 = 0; k0 < KSW; k0 += 32) {
    bf16x8 a0 = *(const bf16x8*)(Ar + k0);
    bf16x8 a1 = *(const bf16x8*)(Ar + 16 * 1024 + k0);
    bf16x8 b0 = *(const bf16x8*)(W0 + k0);
    bf16x8 b1 = *(const bf16x8*)(W1 + k0);
    acc[0][0] = mfma16(a0, b0, acc[0][0]);
    acc[1][0] = mfma16(a1, b0, acc[1][0]);
    acc[0][1] = mfma16(a0, b1, acc[0][1]);
    acc[1][1] = mfma16(a1, b1, acc[1][1]);
  }
#pragma unroll
  for (int mi = 0; mi < 2; ++mi)
#pragma unroll
    for (int nj = 0; nj < 2; ++nj)
#pragma unroll
      for (int reg = 0; reg < 4; ++reg)
        red[(((w * 4) + mi * 2 + nj) * 64 + lane) * 4 + reg] = acc[mi][nj][reg];
  __syncthreads();
  if (w < 4) {
    const int p2 = w, mi = p2 >> 1, nj = p2 & 1;
#pragma unroll
    for (int reg = 0; reg < 4; ++reg) {
      float v = 0.f;
#pragma unroll
      for (int ww = 0; ww < 8; ++ww)
        v += red[(((ww * 4) + p2) * 64 + lane) * 4 + reg];
      int row = mi * 16 + ((lane >> 4) << 2) + reg;
      int col = cb * 32 + nj * 16 + (lane & 15);
      if (HASX) v += p.combX[(size_t)(t * 32 + row) * 1024 + col];
      v += p.comb_b[col];
      p.nbuf[(size_t)row * 1024 + col] = f2b(fmaxf(v, 0.f));
    }
  }
  __syncthreads();
}

// ---------- pinned comb (tf=1): v-half K=1024 + combX + bias, relu -> nbuf ----------
__device__ void comb8_pinned(const Params& p, int cb, int t, const bf16x8* wp, float* red) {
  const int tid = threadIdx.x, w = tid >> 6, lane = tid & 63;
  const int r = lane & 15, kg = (lane >> 4) * 8;
  const int kw0 = w * 128;
  const u16* Ar = p.vb + (size_t)r * 1024 + kw0 + kg;
  f32x4 acc[2][2] = {};
#pragma unroll
  for (int ks = 0; ks < 4; ++ks) {
    bf16x8 a0 = *(const bf16x8*)(Ar + ks * 32);
    bf16x8 a1 = *(const bf16x8*)(Ar + 16 * 1024 + ks * 32);
    acc[0][0] = mfma16(a0, wp[0 + ks], acc[0][0]);
    acc[1][0] = mfma16(a1, wp[0 + ks], acc[1][0]);
    acc[0][1] = mfma16(a0, wp[4 + ks], acc[0][1]);
    acc[1][1] = mfma16(a1, wp[4 + ks], acc[1][1]);
  }
#pragma unroll
  for (int mi = 0; mi < 2; ++mi)
#pragma unroll
    for (int nj = 0; nj < 2; ++nj)
#pragma unroll
      for (int reg = 0; reg < 4; ++reg)
        red[(((w * 4) + mi * 2 + nj) * 64 + lane) * 4 + reg] = acc[mi][nj][reg];
  __syncthreads();
  if (w < 4) {
    const int p2 = w, mi = p2 >> 1, nj = p2 & 1;
#pragma unroll
    for (int reg = 0; reg < 4; ++reg) {
      float v = 0.f;
#pragma unroll
      for (int ww = 0; ww < 8; ++ww)
        v += red[(((ww * 4) + p2) * 64 + lane) * 4 + reg];
      int row = mi * 16 + ((lane >> 4) << 2) + reg;
      int col = cb * 32 + nj * 16 + (lane & 15);
      v += p.combX[(size_t)(t * 32 + row) * 1024 + col] + p.comb_b[col];
      p.nbuf[(size_t)row * 1024 + col] = f2b(fmaxf(v, 0.f));
    }
  }
  __syncthreads();
}

// ---------- log-softmax loss over one bf16 logits row (512 threads) ----------
template <bool AM>
__device__ void loss_row_bf16(const u16* __restrict__ row, int tgt,
                              float* __restrict__ loss_out, int* __restrict__ am_out,
                              float* sh) {
  float* sm = sh;
  float* ss = sh + 512;
  float* sbv = sh + 1024;
  int* sbi = (int*)(sh + 1536);
  const int tid = threadIdx.x;
  float m = -INFINITY, ssum = 0.f, bestv = -INFINITY;
  int besti = 0x7fffffff;
  for (int v = tid; v < V_; v += BT) {
    float x = b2f(row[v]);
    if (x > m) { ssum = ssum * expf(m - x) + 1.f; m = x; }
    else ssum += expf(x - m);
    if (AM) { if (x > bestv) { bestv = x; besti = v; } }
  }
  sm[tid] = m; ss[tid] = ssum;
  if (AM) { sbv[tid] = bestv; sbi[tid] = besti; }
  __syncthreads();
  for (int off = 256; off; off >>= 1) {
    if (tid < off) {
      float m2 = sm[tid + off], s2 = ss[tid + off];
      float mn = fmaxf(sm[tid], m2);
      ss[tid] = ss[tid] * expf(sm[tid] - mn) + s2 * expf(m2 - mn);
      sm[tid] = mn;
      if (AM) {
        float bv2 = sbv[tid + off];
        int bi2 = sbi[tid + off];
        if (bv2 > sbv[tid] || (bv2 == sbv[tid] && bi2 < sbi[tid])) { sbv[tid] = bv2; sbi[tid] = bi2; }
      }
    }
    __syncthreads();
  }
  if (tid == 0) {
    float lp = b2f(row[tgt]) - (sm[0] + logf(ss[0]));
    *loss_out = -lp * (1.f / 32.f);
    if (AM) *am_out = sbi[0];
  }
  __syncthreads();
}

// =================== main persistent kernel ===================
__global__ void binit(unsigned* bar) {
  int i = threadIdx.x;
  if (i < 1024) bar[i] = 0u;
}

__global__ __launch_bounds__(BT, 2) void seq2seq_all(Params p) {
  __shared__ float red_s[16384];   // 64 KB
  __shared__ float sg_s[2048];     // 8 KB
  unsigned bargen = 0;
  const int tid = threadIdx.x, bid = blockIdx.x;
  const int gtid = bid * BT + tid;
  const int gwid = bid * 8 + (tid >> 6);
  const int utf = p.use_tf[0];
  bf16x8 wpin[16];

  // ---------- phase 0: zero state + all weight conversions + gathers (serial, full grid) ----------
  for (int i = gtid; i < B_ * H_; i += NTHR) { p.cbuf[i] = 0.f; p.hbuf[i] = 0; }
  for (int i = gtid; i < G_ * H_ / 4; i += NTHR) {
    float4 v = *(const float4*)(p.enc_Wih + (size_t)i * 4);
    *(ushort4*)(p.wencWih + (size_t)i * 4) = make_ushort4(f2b(v.x), f2b(v.y), f2b(v.z), f2b(v.w));
  }
  for (int i = gtid; i < G_ * H_ / 4; i += NTHR) {
    float4 v = *(const float4*)(p.enc_Whh + (size_t)i * 4);
    *(ushort4*)(p.wencWhh + (size_t)i * 4) = make_ushort4(f2b(v.x), f2b(v.y), f2b(v.z), f2b(v.w));
  }
  for (int i = gtid; i < 2 * H_ * H_ / 4; i += NTHR) {
    float4 v = *(const float4*)(p.comb_W + (size_t)i * 4);
    *(ushort4*)(p.wcomb + (size_t)i * 4) = make_ushort4(f2b(v.x), f2b(v.y), f2b(v.z), f2b(v.w));
  }
  for (int i = gtid; i < S_ * 2 * H_ / 4; i += NTHR) {
    float4 v = *(const float4*)(p.attn_W + (size_t)i * 4);
    *(ushort4*)(p.wattn + (size_t)i * 4) = make_ushort4(f2b(v.x), f2b(v.y), f2b(v.z), f2b(v.w));
  }
  for (int i = gtid; i < V_ * H_ / 4; i += NTHR) {
    float4 v = *(const float4*)(p.out_W + (size_t)i * 4);
    *(ushort4*)(p.wout + (size_t)i * 4) = make_ushort4(f2b(v.x), f2b(v.y), f2b(v.z), f2b(v.w));
  }
  for (int i = gtid; i < G_ * 512; i += NTHR) {   // [dec_Wih | dec_Whh]
    int n = i >> 9, k4 = (i & 511) * 4;
    const float* src = (k4 < 1024) ? (p.dec_Wih + (size_t)n * 1024 + k4)
                                   : (p.dec_Whh + (size_t)n * 1024 + (k4 - 1024));
    float4 v = *(const float4*)src;
    *(ushort4*)(p.wdecG + (size_t)n * 2048 + k4) = make_ushort4(f2b(v.x), f2b(v.y), f2b(v.z), f2b(v.w));
  }
  for (int i = gtid; i < S_ * B_ * 256; i += NTHR) {   // encoder embedding gather
    int m = i >> 8, k4 = (i & 255) * 4;
    float4 v = *(const float4*)(p.enc_emb + (size_t)p.input[m] * 1024 + k4);
    *(ushort4*)(p.Xbf + (size_t)m * 1024 + k4) = make_ushort4(f2b(v.x), f2b(v.y), f2b(v.z), f2b(v.w));
  }
  for (int i = gtid; i < T_ * B_ * 256; i += NTHR) {   // teacher-forced decoder x (relu)
    int m = i >> 8, k4 = (i & 255) * 4;
    int t = m >> 5, b = m & 31;
    int tok = (t == 0) ? 0 : p.target[(t - 1) * 32 + b];
    float4 v = *(const float4*)(p.dec_emb + (size_t)tok * 1024 + k4);
    *(ushort4*)(p.xball + (size_t)m * 1024 + k4) =
        make_ushort4(f2b(fmaxf(v.x, 0.f)), f2b(fmaxf(v.y, 0.f)),
                     f2b(fmaxf(v.z, 0.f)), f2b(fmaxf(v.w, 0.f)));
  }
  gbar(p.bar, ++bargen);

  // ---------- phase 1: batched GEMMs: encX (4096) | combX (1024) | scoreX (64) ----------
  for (int task = gwid; task < 4096 + 1024 + 64; task += NWAVE) {
    if (task < 4096) {
      int mt = task >> 6, ct = task & 63;
      wave_gemm<0>(p.Xbf + (size_t)mt * 32 * 1024, p.wencWih, 1024, 0, ct * 64,
                   nullptr, p.encXbf + (size_t)mt * 32 * G_, G_);
    } else if (task < 5120) {
      int tt = task - 4096, mt = tt >> 4, ct = tt & 15;
      wave_gemm<2>(p.xball + (size_t)mt * 32 * 1024, p.wcomb, 2048, 0, ct * 64,
                   nullptr, p.combX + (size_t)mt * 32 * 1024, 1024);
    } else {
      int mt = task - 5120;
      wave_gemm<3>(p.xball + (size_t)mt * 32 * 1024, p.wattn, 2048, 0, 0,
                   p.attn_b, p.scoreX + (size_t)mt * 32 * 64, 64);
    }
  }
  gbar(p.bar, ++bargen);

  // ---------- phase 2: encoder on blocks 64..127 with pinned encWhh ----------
  if (bid >= 64 && bid < 128)
    load_wpin_gates(p.wencWhh, 1024, 0, bid - 64, wpin);
  int pe = 0;
  for (int s = 0; s < 64; ++s) {
    if (bid >= 64 && bid < 128) {
      const int grp = bid - 64;
      const u16* hprev = p.hbuf + (size_t)pe * B_ * H_;
      u16* hnext = p.hbuf + (size_t)(pe ^ 1) * B_ * H_;
      grouped_gemm8_pinned(hprev, wpin, red_s, sg_s);
      {
        int slot = tid;
        int b = slot >> 4, jj = slot & 15, j = grp * 16 + jj;
        size_t xo = (size_t)(s * 32 + b) * G_;
        float g0 = sg_s[b * 64 + jj]      + b2f(p.encXbf[xo + j])        + p.enc_b[j];
        float g1 = sg_s[b * 64 + 16 + jj] + b2f(p.encXbf[xo + 1024 + j]) + p.enc_b[1024 + j];
        float g2 = sg_s[b * 64 + 32 + jj] + b2f(p.encXbf[xo + 2048 + j]) + p.enc_b[2048 + j];
        float g3 = sg_s[b * 64 + 48 + jj] + b2f(p.encXbf[xo + 3072 + j]) + p.enc_b[3072 + j];
        float ig = sigf(g0), fg = sigf(g1), gg = tanhf(g2), og = sigf(g3);
        float cn = fg * p.cbuf[b * 1024 + j] + ig * gg;
        float hn = og * tanhf(cn);
        p.cbuf[b * 1024 + j] = cn;
        u16 hb2 = f2b(hn);
        hnext[b * 1024 + j] = hb2;
        p.enc_bs[((size_t)b * 1024 + j) * 64 + s] = hb2;
      }
    }
    pe ^= 1;
    gbar(p.bar, ++bargen);
  }

  // ---------- phase 3: decoder ----------
  int pd = pe;   // == 0
  if (utf) {
    if (bid < 32)                      load_wpin_comb(p.wcomb, bid, wpin);
    else if (bid >= 64 && bid < 128)   load_wpin_gates(p.wdecG, 2048, 1024, bid - 64, wpin);
    else if (bid >= 128 && bid < 192)  load_wpin_gates(p.wdecG, 2048, 0, bid - 128, wpin);
    for (int t = 0; t < 64; ++t) {
      const u16* hprev = p.hbuf + (size_t)pd * B_ * H_;
      u16* hnext = p.hbuf + (size_t)(pd ^ 1) * B_ * H_;
      const bool batch = ((t & 7) == 0) && (t > 0);
      // ---- phase A: attention (0..31) || gatesH pinned (64..127)
      // ----          || batch logits part 1 (32..63, 128..255 idle? no: 128..191 busy? They are idle in A)
      if (bid < 32) {
        float* hsh = red_s;            // 1024
        float* ssc = red_s + 1024;     // 512
        float* aw  = red_s + 1536;     // 64
        const int b = bid;
        {
          ushort2 hq = *(const ushort2*)(hprev + (size_t)b * 1024 + tid * 2);
          hsh[tid * 2] = b2f(hq.x);
          hsh[tid * 2 + 1] = b2f(hq.y);
        }
        __syncthreads();
        {
          const int sidx = tid & 63, q = tid >> 6;
          const u16* wr = p.wattn + (size_t)sidx * 2048 + 1024 + q * 128;
          const float* src = hsh + q * 128;
          float acc = 0.f;
          for (int k8 = 0; k8 < 16; ++k8) {
            bf16x8 v = *(const bf16x8*)(wr + k8 * 8);
#pragma unroll
            for (int e = 0; e < 8; ++e)
              acc = fmaf(src[k8 * 8 + e], b2f((u16)v[e]), acc);
          }
          ssc[q * 64 + sidx] = acc;
        }
        __syncthreads();
        if (tid < 64) {
          float sc = p.scoreX[(size_t)(t * 32 + b) * 64 + tid];
#pragma unroll
          for (int q = 0; q < 8; ++q) sc += ssc[q * 64 + tid];
          float m = sc;
#pragma unroll
          for (int off = 32; off; off >>= 1) m = fmaxf(m, __shfl_xor(m, off));
          float e = expf(sc - m), sum = e;
#pragma unroll
          for (int off = 32; off; off >>= 1) sum += __shfl_xor(sum, off);
          aw[tid] = e / sum;
        }
        __syncthreads();
        for (int j = tid; j < 1024; j += BT) {
          const u16* rowp = p.enc_bs + ((size_t)b * 1024 + j) * 64;
          float acc = 0.f;
#pragma unroll
          for (int s8 = 0; s8 < 8; ++s8) {
            bf16x8 v = *(const bf16x8*)(rowp + s8 * 8);
#pragma unroll
            for (int e = 0; e < 8; ++e)
              acc = fmaf(aw[s8 * 8 + e], b2f((u16)v[e]), acc);
          }
          p.vb[(size_t)b * 1024 + j] = f2b(acc);
        }
      } else if (bid >= 64 && bid < 128) {
        const int grp = bid - 64;
        grouped_gemm8_pinned(hprev, wpin, red_s, sg_s);
        {
          int slot = tid;
          int b = slot >> 4, jj = slot & 15, j = grp * 16 + jj;
          p.gatesH[(size_t)b * G_ + j]        = sg_s[b * 64 + jj];
          p.gatesH[(size_t)b * G_ + 1024 + j] = sg_s[b * 64 + 16 + jj];
          p.gatesH[(size_t)b * G_ + 2048 + j] = sg_s[b * 64 + 32 + jj];
          p.gatesH[(size_t)b * G_ + 3072 + j] = sg_s[b * 64 + 48 + jj];
        }
      } else if (batch) {
        // batch logits part 1: tasks [0, 2000) on 160 idle blocks (32..63, 128..255)
        const int lb = (bid < 64) ? (bid - 32) : (bid - 96);   // 0..31, 32..159
        const u16* Abase = p.hall + (size_t)(t - 8) * 32 * 1024;
        for (int task = lb * 8 + (tid >> 6); task < 2000; task += 160 * 8) {
          int ct = task >> 3, mt = task & 7;
          wave_gemm<1>(Abase + (size_t)mt * 32 * 1024, p.wout, 1024, 0, ct * 64,
                       p.out_b, p.ring + (size_t)mt * 32 * V_, V_);
        }
      }
      gbar(p.bar, ++bargen);
      // ---- phase B: comb-v pinned (0..31) || batch logits part 2 (32..255) ----
      if (bid < 32) {
        comb8_pinned(p, bid, t, wpin, red_s);
      } else if (batch) {
        const u16* Abase = p.hall + (size_t)(t - 8) * 32 * 1024;
        for (int task = 2000 + (bid - 32) * 8 + (tid >> 6); task < 4000; task += 224 * 8) {
          int ct = task >> 3, mt = task & 7;
          wave_gemm<1>(Abase + (size_t)mt * 32 * 1024, p.wout, 1024, 0, ct * 64,
                       p.out_b, p.ring + (size_t)mt * 32 * V_, V_);
        }
      }
      gbar(p.bar, ++bargen);
      // ---- phase C: gates-x pinned + LSTM (128..191) || batch loss (192..255) ----
      if (bid >= 128 && bid < 192) {
        const int grp = bid - 128;
        grouped_gemm8_pinned(p.nbuf, wpin, red_s, sg_s);
        {
          int slot = tid;
          int b = slot >> 4, jj = slot & 15, j = grp * 16 + jj;
          float g0 = sg_s[b * 64 + jj]      + p.gatesH[(size_t)b * G_ + j]        + p.dec_b[j];
          float g1 = sg_s[b * 64 + 16 + jj] + p.gatesH[(size_t)b * G_ + 1024 + j] + p.dec_b[1024 + j];
          float g2 = sg_s[b * 64 + 32 + jj] + p.gatesH[(size_t)b * G_ + 2048 + j] + p.dec_b[2048 + j];
          float g3 = sg_s[b * 64 + 48 + jj] + p.gatesH[(size_t)b * G_ + 3072 + j] + p.dec_b[3072 + j];
          float ig = sigf(g0), fg = sigf(g1), gg = tanhf(g2), og = sigf(g3);
          float cn = fg * p.cbuf[b * 1024 + j] + ig * gg;
          float hn = og * tanhf(cn);
          p.cbuf[b * 1024 + j] = cn;
          u16 hb2 = f2b(hn);
          hnext[b * 1024 + j] = hb2;
          p.hall[((size_t)t * 32 + b) * 1024 + j] = hb2;
        }
      } else if (bid >= 192 && batch) {
        int base = (bid - 192) * 4;
        for (int rr = 0; rr < 4; ++rr) {
          int m = base + rr, gm = (t - 8) * 32 + m;
          loss_row_bf16<false>(p.ring + (size_t)m * V_, p.target[gm], &p.loss_p[gm],
                               nullptr, red_s);
        }
      }
      gbar(p.bar, ++bargen);
      pd ^= 1;
    }
    // ---- E1: batched logits for h[56..63] on all 256 blocks ----
    {
      const u16* Abase = p.hall + (size_t)56 * 32 * 1024;
      for (int task = bid * 8 + (tid >> 6); task < 4000; task += 2048) {
        int ct = task >> 3, mt = task & 7;
        wave_gemm<1>(Abase + (size_t)mt * 32 * 1024, p.wout, 1024, 0, ct * 64,
                     p.out_b, p.ring + (size_t)mt * 32 * V_, V_);
      }
    }
    gbar(p.bar, ++bargen);
    // ---- E2: loss rows 1792..2047 on blocks 0..127 ----
    if (bid < 128) {
      for (int rr = 0; rr < 2; ++rr) {
        int m = bid * 2 + rr, gm = 56 * 32 + m;
        loss_row_bf16<false>(p.ring + (size_t)m * V_, p.target[gm], &p.loss_p[gm],
                             nullptr, red_s);
      }
    }
    gbar(p.bar, ++bargen);
  } else {
    // ---- tf=0: per-step feedback path (R10-identical) ----
    for (int t = 0; t < 64; ++t) {
      const u16* hprev = p.hbuf + (size_t)pd * B_ * H_;
      u16* hnext = p.hbuf + (size_t)(pd ^ 1) * B_ * H_;
      if (bid < 32) {
        float* xsh = red_s;
        float* hsh = red_s + 1024;
        float* ssc = red_s + 2048;
        float* aw  = red_s + 2560;
        const int b = bid;
        int tok = (t > 0) ? p.prevtok[b] : 0;
        {
          float2 v = *(const float2*)(p.dec_emb + (size_t)tok * 1024 + tid * 2);
          float x0 = fmaxf(v.x, 0.f), x1 = fmaxf(v.y, 0.f);
          xsh[tid * 2] = x0; xsh[tid * 2 + 1] = x1;
          *(ushort2*)(p.xb + (size_t)b * 1024 + tid * 2) = make_ushort2(f2b(x0), f2b(x1));
          ushort2 hq = *(const ushort2*)(hprev + (size_t)b * 1024 + tid * 2);
          hsh[tid * 2] = b2f(hq.x); hsh[tid * 2 + 1] = b2f(hq.y);
        }
        __syncthreads();
        {
          const int sidx = tid & 63, q = tid >> 6;
          const u16* wr = p.wattn + (size_t)sidx * 2048 + q * 256;
          const float* src = (q < 4) ? (xsh + q * 256) : (hsh + (q - 4) * 256);
          float acc = 0.f;
          for (int k8 = 0; k8 < 32; ++k8) {
            bf16x8 v = *(const bf16x8*)(wr + k8 * 8);
#pragma unroll
            for (int e = 0; e < 8; ++e)
              acc = fmaf(src[k8 * 8 + e], b2f((u16)v[e]), acc);
          }
          ssc[q * 64 + sidx] = acc;
        }
        __syncthreads();
        if (tid < 64) {
          float sc = p.attn_b[tid];
#pragma unroll
          for (int q = 0; q < 8; ++q) sc += ssc[q * 64 + tid];
          float m = sc;
#pragma unroll
          for (int off = 32; off; off >>= 1) m = fmaxf(m, __shfl_xor(m, off));
          float e = expf(sc - m), sum = e;
#pragma unroll
          for (int off = 32; off; off >>= 1) sum += __shfl_xor(sum, off);
          aw[tid] = e / sum;
        }
        __syncthreads();
        for (int j = tid; j < 1024; j += BT) {
          const u16* rowp = p.enc_bs + ((size_t)b * 1024 + j) * 64;
          float acc = 0.f;
#pragma unroll
          for (int s8 = 0; s8 < 8; ++s8) {
            bf16x8 v = *(const bf16x8*)(rowp + s8 * 8);
#pragma unroll
            for (int e = 0; e < 8; ++e)
              acc = fmaf(aw[s8 * 8 + e], b2f((u16)v[e]), acc);
          }
          p.vb[(size_t)b * 1024 + j] = f2b(acc);
        }
      } else if (bid >= 64 && bid < 128) {
        const int grp = bid - 64;
        grouped_gemm8(hprev, p.wdecG, 2048, 1024, grp, red_s, sg_s);
        {
          int slot = tid;
          int b = slot >> 4, jj = slot & 15, j = grp * 16 + jj;
          p.gatesH[(size_t)b * G_ + j]        = sg_s[b * 64 + jj];
          p.gatesH[(size_t)b * G_ + 1024 + j] = sg_s[b * 64 + 16 + jj];
          p.gatesH[(size_t)b * G_ + 2048 + j] = sg_s[b * 64 + 32 + jj];
          p.gatesH[(size_t)b * G_ + 3072 + j] = sg_s[b * 64 + 48 + jj];
        }
      }
      gbar(p.bar, ++bargen);
      if (bid < 32) comb8<2048, false>(p, bid, t, red_s);
      gbar(p.bar, ++bargen);
      if (bid < 64) {
        grouped_gemm8(p.nbuf, p.wdecG, 2048, 0, bid, red_s, sg_s);
        {
          int slot = tid;
          int b = slot >> 4, jj = slot & 15, j = bid * 16 + jj;
          float g0 = sg_s[b * 64 + jj]      + p.gatesH[(size_t)b * G_ + j]        + p.dec_b[j];
          float g1 = sg_s[b * 64 + 16 + jj] + p.gatesH[(size_t)b * G_ + 1024 + j] + p.dec_b[1024 + j];
          float g2 = sg_s[b * 64 + 32 + jj] + p.gatesH[(size_t)b * G_ + 2048 + j] + p.dec_b[2048 + j];
          float g3 = sg_s[b * 64 + 48 + jj] + p.gatesH[(size_t)b * G_ + 3072 + j] + p.dec_b[3072 + j];
          float ig = sigf(g0), fg = sigf(g1), gg = tanhf(g2), og = sigf(g3);
          float cn = fg * p.cbuf[b * 1024 + j] + ig * gg;
          float hn = og * tanhf(cn);
          p.cbuf[b * 1024 + j] = cn;
          u16 hb2 = f2b(hn);
          hnext[b * 1024 + j] = hb2;
          p.hall[((size_t)t * 32 + b) * 1024 + j] = hb2;
        }
      }
      gbar(p.bar, ++bargen);
      pd ^= 1;
      for (int task = gwid; task < 500; task += NWAVE)
        wave_gemm<1>(p.hbuf + (size_t)pd * B_ * H_, p.wout, 1024, 0, task * 64,
                     p.out_b, p.ring, V_);
      gbar(p.bar, ++bargen);
      if (bid < 32)
        loss_row_bf16<true>(p.ring + (size_t)bid * V_, p.target[t * 32 + bid],
                            &p.loss_p[t * 32 + bid], &p.prevtok[bid], red_s);
      gbar(p.bar, ++bargen);
    }
  }

  // ---------- final sum ----------
  if (bid == 0) {
    float a = 0.f;
    for (int i = tid; i < T_ * B_; i += BT) a += p.loss_p[i];
    red_s[tid] = a;
    __syncthreads();
    for (int off = 256; off; off >>= 1) {
      if (tid < off) red_s[tid] += red_s[tid + off];
      __syncthreads();
    }
    if (tid == 0) p.out[0] = red_s[0];
  }
}

// ---------------- host launch ----------------
extern "C" void kernel_launch(void* const* d_in, const int* in_sizes, int n_in,
                              void* d_out, int out_size, void* d_ws, size_t ws_size,
                              hipStream_t stream) {
  (void)in_sizes; (void)n_in; (void)out_size; (void)ws_size;
  Params p;
  p.input   = (const int*)d_in[0];
  p.target  = (const int*)d_in[1];
  p.use_tf  = (const int*)d_in[2];
  p.enc_emb = (const float*)d_in[3];
  p.enc_Wih = (const float*)d_in[4];
  p.enc_Whh = (const float*)d_in[5];
  p.enc_b   = (const float*)d_in[6];
  p.dec_emb = (const float*)d_in[7];
  p.dec_Wih = (const float*)d_in[8];
  p.dec_Whh = (const float*)d_in[9];
  p.dec_b   = (const float*)d_in[10];
  p.attn_W  = (const float*)d_in[11];
  p.attn_b  = (const float*)d_in[12];
  p.comb_W  = (const float*)d_in[13];
  p.comb_b  = (const float*)d_in[14];
  p.out_W   = (const float*)d_in[15];
  p.out_b   = (const float*)d_in[16];
  p.out     = (float*)d_out;

  char* ws = (char*)d_ws;
  size_t off = 0;
  auto alloc = [&](size_t bytes) {
    void* q = ws + off;
    off += ((bytes + 255) & ~(size_t)255);
    return q;
  };
  p.Xbf     = (u16*)alloc((size_t)S_ * B_ * H_ * 2);       // 4.2 MB
  p.encXbf  = (u16*)alloc((size_t)S_ * B_ * G_ * 2);       // 16.8 MB (ring aliases after encoder)
  p.enc_bs  = (u16*)alloc((size_t)B_ * H_ * S_ * 2);       // 4.2 MB
  p.hall    = (u16*)alloc((size_t)T_ * B_ * H_ * 2);       // 4.2 MB
  p.hbuf    = (u16*)alloc((size_t)2 * B_ * H_ * 2);
  p.xb      = (u16*)alloc((size_t)B_ * H_ * 2);
  p.vb      = (u16*)alloc((size_t)B_ * H_ * 2);
  p.nbuf    = (u16*)alloc((size_t)B_ * H_ * 2);
  p.xball   = (u16*)alloc((size_t)T_ * B_ * H_ * 2);       // 4.2 MB
  p.combX   = (float*)alloc((size_t)T_ * B_ * H_ * 4);     // 8.4 MB
  p.scoreX  = (float*)alloc((size_t)T_ * B_ * 64 * 4);     // 0.5 MB
  p.gatesH  = (float*)alloc((size_t)B_ * G_ * 4);          // 0.5 MB
  p.cbuf    = (float*)alloc((size_t)B_ * H_ * 4);
  p.loss_p  = (float*)alloc((size_t)T_ * B_ * 4);
  p.prevtok = (int*)alloc(B_ * 4);
  p.bar     = (unsigned*)alloc(4096);
  p.wencWih = (u16*)alloc((size_t)G_ * H_ * 2);            // 8.4 MB
  p.wencWhh = (u16*)alloc((size_t)G_ * H_ * 2);            // 8.4 MB
  p.wdecG   = (u16*)alloc((size_t)G_ * 2 * H_ * 2);        // 16.8 MB
  p.wcomb   = (u16*)alloc((size_t)H_ * 2 * H_ * 2);        // 4.2 MB
  p.wattn   = (u16*)alloc((size_t)S_ * 2 * H_ * 2);        // 0.26 MB
  p.wout    = (u16*)alloc((size_t)V_ * H_ * 2);            // 65.5 MB
  // logits ring: 256 rows x 32000 bf16 = 16.38 MB, aliases dead-after-encoder encXbf
  p.ring = p.encXbf;
  // total ~147 MB

  binit<<<1, 1024, 0, stream>>>(p.bar);
  seq2seq_all<<<NB, BT, 0, stream>>>(p);
}

// Round 14
// 5813.830 us; speedup vs baseline: 4.6060x; 4.6060x over previous
//
#include <hip/hip_runtime.h>
#include <cmath>
#include <cstddef>

// S=T=64, B=32, H=1024, G=4H, V=32000
constexpr int S_ = 64, T_ = 64, B_ = 32, H_ = 1024, G_ = 4096, V_ = 32000;
constexpr int NB = 256, BT = 512, NTHR = NB * BT, NWAVE = NB * 8;

typedef unsigned short u16;   // bf16 bit pattern
typedef __attribute__((ext_vector_type(8))) short bf16x8;
typedef __attribute__((ext_vector_type(4))) float f32x4;

__device__ __forceinline__ float sigf(float x) { return 1.f / (1.f + expf(-x)); }
__device__ __forceinline__ float b2f(u16 u) { return __uint_as_float(((unsigned)u) << 16); }
__device__ __forceinline__ u16 f2b(float f) {
  unsigned u = __float_as_uint(f);
  return (u16)((u + 0x7fff + ((u >> 16) & 1)) >> 16);  // RNE
}
__device__ __forceinline__ f32x4 mfma16(bf16x8 a, bf16x8 b, f32x4 c) {
  return __builtin_amdgcn_mfma_f32_16x16x32_bf16(a, b, c, 0, 0, 0);
}

struct Params {
  const int *input, *target, *use_tf;
  const float *enc_emb, *enc_Wih, *enc_Whh, *enc_b;
  const float *dec_emb, *dec_Wih, *dec_Whh, *dec_b;
  const float *attn_W, *attn_b, *comb_W, *comb_b, *out_W, *out_b;
  float* out;
  u16 *Xbf, *encXbf, *enc_bs, *hall, *hbuf, *xb, *vb, *nbuf, *xball, *ring;
  float *combX, *scoreX, *gatesH, *cbuf, *loss_p;
  int* prevtok;
  u16 *wencWih, *wencWhh, *wdecG, *wcomb, *wattn, *wout;
  unsigned* bar;
};

// ---------- two-level device-scope grid barrier (R10-proven, s_sleep backoff) ----------
__device__ __forceinline__ void gbar(unsigned* bar, unsigned target) {
  __syncthreads();
  if (threadIdx.x == 0) {
    __threadfence();
    int g = blockIdx.x >> 4;
    unsigned a = __hip_atomic_fetch_add(bar + g * 16, 1u, __ATOMIC_ACQ_REL,
                                        __HIP_MEMORY_SCOPE_AGENT);
    if (a == 15u) {
      unsigned r = __hip_atomic_fetch_add(bar + 256, 1u, __ATOMIC_ACQ_REL,
                                          __HIP_MEMORY_SCOPE_AGENT);
      if (r == 15u) {
        for (int i = 0; i < 16; ++i)
          __hip_atomic_store(bar + i * 16, 0u, __ATOMIC_RELAXED, __HIP_MEMORY_SCOPE_AGENT);
        __hip_atomic_store(bar + 256, 0u, __ATOMIC_RELAXED, __HIP_MEMORY_SCOPE_AGENT);
        __hip_atomic_store(bar + 272, target, __ATOMIC_RELEASE, __HIP_MEMORY_SCOPE_AGENT);
      }
    }
    while (__hip_atomic_load(bar + 272, __ATOMIC_ACQUIRE, __HIP_MEMORY_SCOPE_AGENT) < target)
      __builtin_amdgcn_s_sleep(2);
  }
  __syncthreads();
}

// ---------- per-wave 32x64 tile GEMM, K=1024 ----------
// EPI: 0 bf16, 1 bf16+bias, 2 f32, 3 f32+bias
template <int EPI>
__device__ void wave_gemm(const u16* __restrict__ A, const u16* __restrict__ W,
                          int ldw, int wkoff, int colbase, const float* __restrict__ bias,
                          void* __restrict__ outp, int ldo) {
  const int lane = threadIdx.x & 63;
  const int r = lane & 15, kg = (lane >> 4) * 8;
  const u16* Ar = A + (size_t)r * 1024 + kg;
  const u16* Wr = W + (size_t)(colbase + r) * ldw + wkoff + kg;
  f32x4 acc[2][4] = {};
#pragma unroll 2
  for (int k0 = 0; k0 < 1024; k0 += 32) {
    bf16x8 a0 = *(const bf16x8*)(Ar + k0);
    bf16x8 a1 = *(const bf16x8*)(Ar + 16 * 1024 + k0);
    bf16x8 b0 = *(const bf16x8*)(Wr + k0);
    bf16x8 b1 = *(const bf16x8*)(Wr + (size_t)16 * ldw + k0);
    bf16x8 b2 = *(const bf16x8*)(Wr + (size_t)32 * ldw + k0);
    bf16x8 b3 = *(const bf16x8*)(Wr + (size_t)48 * ldw + k0);
    acc[0][0] = mfma16(a0, b0, acc[0][0]);
    acc[1][0] = mfma16(a1, b0, acc[1][0]);
    acc[0][1] = mfma16(a0, b1, acc[0][1]);
    acc[1][1] = mfma16(a1, b1, acc[1][1]);
    acc[0][2] = mfma16(a0, b2, acc[0][2]);
    acc[1][2] = mfma16(a1, b2, acc[1][2]);
    acc[0][3] = mfma16(a0, b3, acc[0][3]);
    acc[1][3] = mfma16(a1, b3, acc[1][3]);
  }
#pragma unroll
  for (int mi = 0; mi < 2; ++mi)
#pragma unroll
    for (int nj = 0; nj < 4; ++nj) {
      int col = colbase + nj * 16 + (lane & 15);
      int row0 = mi * 16 + ((lane >> 4) << 2);
#pragma unroll
      for (int reg = 0; reg < 4; ++reg) {
        float v = acc[mi][nj][reg];
        if (EPI == 1 || EPI == 3) v += bias[col];
        if (EPI <= 1) ((u16*)outp)[(size_t)(row0 + reg) * ldo + col] = f2b(v);
        else ((float*)outp)[(size_t)(row0 + reg) * ldo + col] = v;
      }
    }
}

// ---------- streamed block 32x64 grouped-col GEMM (tf=0 path) ----------
__device__ void grouped_gemm8(const u16* __restrict__ A, const u16* __restrict__ Wm,
                              int ldw, int wkoff, int grp, float* red, float* sg) {
  const int tid = threadIdx.x, w = tid >> 6, lane = tid & 63;
  const int r = lane & 15, kg = (lane >> 4) * 8;
  const int kw0 = w * 128;
  const u16* Ar = A + (size_t)r * 1024 + kw0 + kg;
  const u16* W0 = Wm + (size_t)(grp * 16 + r) * ldw + wkoff + kw0 + kg;
  const u16* W1 = W0 + (size_t)1024 * ldw;
  const u16* W2 = W0 + (size_t)2048 * ldw;
  const u16* W3 = W0 + (size_t)3072 * ldw;
  f32x4 acc[2][4] = {};
#pragma unroll
  for (int k0 = 0; k0 < 128; k0 += 32) {
    bf16x8 a0 = *(const bf16x8*)(Ar + k0);
    bf16x8 a1 = *(const bf16x8*)(Ar + 16 * 1024 + k0);
    bf16x8 b0 = *(const bf16x8*)(W0 + k0);
    bf16x8 b1 = *(const bf16x8*)(W1 + k0);
    bf16x8 b2 = *(const bf16x8*)(W2 + k0);
    bf16x8 b3 = *(const bf16x8*)(W3 + k0);
    acc[0][0] = mfma16(a0, b0, acc[0][0]);
    acc[1][0] = mfma16(a1, b0, acc[1][0]);
    acc[0][1] = mfma16(a0, b1, acc[0][1]);
    acc[1][1] = mfma16(a1, b1, acc[1][1]);
    acc[0][2] = mfma16(a0, b2, acc[0][2]);
    acc[1][2] = mfma16(a1, b2, acc[1][2]);
    acc[0][3] = mfma16(a0, b3, acc[0][3]);
    acc[1][3] = mfma16(a1, b3, acc[1][3]);
  }
#pragma unroll
  for (int mi = 0; mi < 2; ++mi)
#pragma unroll
    for (int nj = 0; nj < 4; ++nj)
#pragma unroll
      for (int reg = 0; reg < 4; ++reg)
        red[(((w * 8) + mi * 4 + nj) * 64 + lane) * 4 + reg] = acc[mi][nj][reg];
  __syncthreads();
  {
    const int p2 = w;
    const int mi = p2 >> 2, nj = p2 & 3;
#pragma unroll
    for (int reg = 0; reg < 4; ++reg) {
      float v = 0.f;
#pragma unroll
      for (int ww = 0; ww < 8; ++ww)
        v += red[(((ww * 8) + p2) * 64 + lane) * 4 + reg];
      sg[(mi * 16 + ((lane >> 4) << 2) + reg) * 64 + nj * 16 + (lane & 15)] = v;
    }
  }
  __syncthreads();
}

// ---------- pinned-weight loaders ----------
__device__ __forceinline__ void load_wpin_gates(const u16* Wm, int ldw, int wkoff,
                                                int grp, bf16x8* wp) {
  const int w = threadIdx.x >> 6, lane = threadIdx.x & 63;
  const int r = lane & 15, kg = (lane >> 4) * 8;
  const int kw0 = w * 128;
  const u16* W0 = Wm + (size_t)(grp * 16 + r) * ldw + wkoff + kw0 + kg;
#pragma unroll
  for (int q = 0; q < 4; ++q)
#pragma unroll
    for (int ks = 0; ks < 4; ++ks)
      wp[q * 4 + ks] = *(const bf16x8*)(W0 + (size_t)(q * 1024) * ldw + ks * 32);
}

__device__ __forceinline__ void load_wpin_comb(const u16* Wm, int cb, bf16x8* wp) {
  const int w = threadIdx.x >> 6, lane = threadIdx.x & 63;
  const int r = lane & 15, kg = (lane >> 4) * 8;
  const int kw0 = w * 128;
  const u16* W0 = Wm + (size_t)(cb * 32 + r) * 2048 + 1024 + kw0 + kg;
#pragma unroll
  for (int h = 0; h < 2; ++h)
#pragma unroll
    for (int ks = 0; ks < 4; ++ks)
      wp[h * 4 + ks] = *(const bf16x8*)(W0 + (size_t)(h * 16) * 2048 + ks * 32);
}

// ---------- pinned grouped-col GEMM -> sg[32][64] ----------
__device__ void grouped_gemm8_pinned(const u16* __restrict__ A, const bf16x8* wp,
                                     float* red, float* sg) {
  const int tid = threadIdx.x, w = tid >> 6, lane = tid & 63;
  const int r = lane & 15, kg = (lane >> 4) * 8;
  const int kw0 = w * 128;
  const u16* Ar = A + (size_t)r * 1024 + kw0 + kg;
  f32x4 acc[2][4] = {};
#pragma unroll
  for (int ks = 0; ks < 4; ++ks) {
    bf16x8 a0 = *(const bf16x8*)(Ar + ks * 32);
    bf16x8 a1 = *(const bf16x8*)(Ar + 16 * 1024 + ks * 32);
    acc[0][0] = mfma16(a0, wp[0 + ks], acc[0][0]);
    acc[1][0] = mfma16(a1, wp[0 + ks], acc[1][0]);
    acc[0][1] = mfma16(a0, wp[4 + ks], acc[0][1]);
    acc[1][1] = mfma16(a1, wp[4 + ks], acc[1][1]);
    acc[0][2] = mfma16(a0, wp[8 + ks], acc[0][2]);
    acc[1][2] = mfma16(a1, wp[8 + ks], acc[1][2]);
    acc[0][3] = mfma16(a0, wp[12 + ks], acc[0][3]);
    acc[1][3] = mfma16(a1, wp[12 + ks], acc[1][3]);
  }
#pragma unroll
  for (int mi = 0; mi < 2; ++mi)
#pragma unroll
    for (int nj = 0; nj < 4; ++nj)
#pragma unroll
      for (int reg = 0; reg < 4; ++reg)
        red[(((w * 8) + mi * 4 + nj) * 64 + lane) * 4 + reg] = acc[mi][nj][reg];
  __syncthreads();
  {
    const int p2 = w;
    const int mi = p2 >> 2, nj = p2 & 3;
#pragma unroll
    for (int reg = 0; reg < 4; ++reg) {
      float v = 0.f;
#pragma unroll
      for (int ww = 0; ww < 8; ++ww)
        v += red[(((ww * 8) + p2) * 64 + lane) * 4 + reg];
      sg[(mi * 16 + ((lane >> 4) << 2) + reg) * 64 + nj * 16 + (lane & 15)] = v;
    }
  }
  __syncthreads();
}

// ---------- streamed comb (tf=0): K=2048 over [xb|vb] ----------
template <int KTOT, bool HASX>
__device__ void comb8(const Params& p, int cb, int t, float* red) {
  const int tid = threadIdx.x, w = tid >> 6, lane = tid & 63;
  const int r = lane & 15, kg = (lane >> 4) * 8;
  constexpr int KSW = KTOT / 8;
  const int kw0 = w * KSW;
  const u16* Abase;
  int koff;
  if (KTOT == 2048) { Abase = (kw0 < 1024) ? p.xb : p.vb; koff = kw0 & 1023; }
  else { Abase = p.vb; koff = kw0; }
  const u16* Ar = Abase + (size_t)r * 1024 + koff + kg;
  const int wko = (KTOT == 1024) ? 1024 : 0;
  const u16* W0 = p.wcomb + (size_t)(cb * 32 + r) * 2048 + wko + kw0 + kg;
  const u16* W1 = W0 + (size_t)16 * 2048;
  f32x4 acc[2][2] = {};
#pragma unroll
  for (int k0 = 0; k0 < KSW; k0 += 32) {
    bf16x8 a0 = *(const bf16x8*)(Ar + k0);
    bf16x8 a1 = *(const bf16x8*)(Ar + 16 * 1024 + k0);
    bf16x8 b0 = *(const bf16x8*)(W0 + k0);
    bf16x8 b1 = *(const bf16x8*)(W1 + k0);
    acc[0][0] = mfma16(a0, b0, acc[0][0]);
    acc[1][0] = mfma16(a1, b0, acc[1][0]);
    acc[0][1] = mfma16(a0, b1, acc[0][1]);
    acc[1][1] = mfma16(a1, b1, acc[1][1]);
  }
#pragma unroll
  for (int mi = 0; mi < 2; ++mi)
#pragma unroll
    for (int nj = 0; nj < 2; ++nj)
#pragma unroll
      for (int reg = 0; reg < 4; ++reg)
        red[(((w * 4) + mi * 2 + nj) * 64 + lane) * 4 + reg] = acc[mi][nj][reg];
  __syncthreads();
  if (w < 4) {
    const int p2 = w, mi = p2 >> 1, nj = p2 & 1;
#pragma unroll
    for (int reg = 0; reg < 4; ++reg) {
      float v = 0.f;
#pragma unroll
      for (int ww = 0; ww < 8; ++ww)
        v += red[(((ww * 4) + p2) * 64 + lane) * 4 + reg];
      int row = mi * 16 + ((lane >> 4) << 2) + reg;
      int col = cb * 32 + nj * 16 + (lane & 15);
      if (HASX) v += p.combX[(size_t)(t * 32 + row) * 1024 + col];
      v += p.comb_b[col];
      p.nbuf[(size_t)row * 1024 + col] = f2b(fmaxf(v, 0.f));
    }
  }
  __syncthreads();
}

// ---------- pinned comb (tf=1): v-half K=1024 + combX + bias, relu -> nbuf ----------
__device__ void comb8_pinned(const Params& p, int cb, int t, const bf16x8* wp, float* red) {
  const int tid = threadIdx.x, w = tid >> 6, lane = tid & 63;
  const int r = lane & 15, kg = (lane >> 4) * 8;
  const int kw0 = w * 128;
  const u16* Ar = p.vb + (size_t)r * 1024 + kw0 + kg;
  f32x4 acc[2][2] = {};
#pragma unroll
  for (int ks = 0; ks < 4; ++ks) {
    bf16x8 a0 = *(const bf16x8*)(Ar + ks * 32);
    bf16x8 a1 = *(const bf16x8*)(Ar + 16 * 1024 + ks * 32);
    acc[0][0] = mfma16(a0, wp[0 + ks], acc[0][0]);
    acc[1][0] = mfma16(a1, wp[0 + ks], acc[1][0]);
    acc[0][1] = mfma16(a0, wp[4 + ks], acc[0][1]);
    acc[1][1] = mfma16(a1, wp[4 + ks], acc[1][1]);
  }
#pragma unroll
  for (int mi = 0; mi < 2; ++mi)
#pragma unroll
    for (int nj = 0; nj < 2; ++nj)
#pragma unroll
      for (int reg = 0; reg < 4; ++reg)
        red[(((w * 4) + mi * 2 + nj) * 64 + lane) * 4 + reg] = acc[mi][nj][reg];
  __syncthreads();
  if (w < 4) {
    const int p2 = w, mi = p2 >> 1, nj = p2 & 1;
#pragma unroll
    for (int reg = 0; reg < 4; ++reg) {
      float v = 0.f;
#pragma unroll
      for (int ww = 0; ww < 8; ++ww)
        v += red[(((ww * 4) + p2) * 64 + lane) * 4 + reg];
      int row = mi * 16 + ((lane >> 4) << 2) + reg;
      int col = cb * 32 + nj * 16 + (lane & 15);
      v += p.combX[(size_t)(t * 32 + row) * 1024 + col] + p.comb_b[col];
      p.nbuf[(size_t)row * 1024 + col] = f2b(fmaxf(v, 0.f));
    }
  }
  __syncthreads();
}

// ---------- log-softmax loss over one bf16 logits row (512 threads) ----------
template <bool AM>
__device__ void loss_row_bf16(const u16* __restrict__ row, int tgt,
                              float* __restrict__ loss_out, int* __restrict__ am_out,
                              float* sh) {
  float* sm = sh;
  float* ss = sh + 512;
  float* sbv = sh + 1024;
  int* sbi = (int*)(sh + 1536);
  const int tid = threadIdx.x;
  float m = -INFINITY, ssum = 0.f, bestv = -INFINITY;
  int besti = 0x7fffffff;
  for (int v = tid; v < V_; v += BT) {
    float x = b2f(row[v]);
    if (x > m) { ssum = ssum * expf(m - x) + 1.f; m = x; }
    else ssum += expf(x - m);
    if (AM) { if (x > bestv) { bestv = x; besti = v; } }
  }
  sm[tid] = m; ss[tid] = ssum;
  if (AM) { sbv[tid] = bestv; sbi[tid] = besti; }
  __syncthreads();
  for (int off = 256; off; off >>= 1) {
    if (tid < off) {
      float m2 = sm[tid + off], s2 = ss[tid + off];
      float mn = fmaxf(sm[tid], m2);
      ss[tid] = ss[tid] * expf(sm[tid] - mn) + s2 * expf(m2 - mn);
      sm[tid] = mn;
      if (AM) {
        float bv2 = sbv[tid + off];
        int bi2 = sbi[tid + off];
        if (bv2 > sbv[tid] || (bv2 == sbv[tid] && bi2 < sbi[tid])) { sbv[tid] = bv2; sbi[tid] = bi2; }
      }
    }
    __syncthreads();
  }
  if (tid == 0) {
    float lp = b2f(row[tgt]) - (sm[0] + logf(ss[0]));
    *loss_out = -lp * (1.f / 32.f);
    if (AM) *am_out = sbi[0];
  }
  __syncthreads();
}

// =================== main persistent kernel ===================
__global__ void binit(unsigned* bar) {
  int i = threadIdx.x;
  if (i < 288) bar[i] = 0u;
}

__global__ __launch_bounds__(BT, 2) void seq2seq_all(Params p) {
  __shared__ float red_s[16384];   // 64 KB
  __shared__ float sg_s[2048];     // 8 KB
  unsigned bargen = 0;
  const int tid = threadIdx.x, bid = blockIdx.x;
  const int gtid = bid * BT + tid;
  const int gwid = bid * 8 + (tid >> 6);
  const int utf = p.use_tf[0];
  bf16x8 wpin[16];

  // ---------- phase 0: zero state + all weight conversions + gathers ----------
  for (int i = gtid; i < B_ * H_; i += NTHR) { p.cbuf[i] = 0.f; p.hbuf[i] = 0; }
  for (int i = gtid; i < G_ * H_ / 4; i += NTHR) {
    float4 v = *(const float4*)(p.enc_Wih + (size_t)i * 4);
    *(ushort4*)(p.wencWih + (size_t)i * 4) = make_ushort4(f2b(v.x), f2b(v.y), f2b(v.z), f2b(v.w));
  }
  for (int i = gtid; i < G_ * H_ / 4; i += NTHR) {
    float4 v = *(const float4*)(p.enc_Whh + (size_t)i * 4);
    *(ushort4*)(p.wencWhh + (size_t)i * 4) = make_ushort4(f2b(v.x), f2b(v.y), f2b(v.z), f2b(v.w));
  }
  for (int i = gtid; i < 2 * H_ * H_ / 4; i += NTHR) {
    float4 v = *(const float4*)(p.comb_W + (size_t)i * 4);
    *(ushort4*)(p.wcomb + (size_t)i * 4) = make_ushort4(f2b(v.x), f2b(v.y), f2b(v.z), f2b(v.w));
  }
  for (int i = gtid; i < S_ * 2 * H_ / 4; i += NTHR) {
    float4 v = *(const float4*)(p.attn_W + (size_t)i * 4);
    *(ushort4*)(p.wattn + (size_t)i * 4) = make_ushort4(f2b(v.x), f2b(v.y), f2b(v.z), f2b(v.w));
  }
  for (int i = gtid; i < V_ * H_ / 4; i += NTHR) {
    float4 v = *(const float4*)(p.out_W + (size_t)i * 4);
    *(ushort4*)(p.wout + (size_t)i * 4) = make_ushort4(f2b(v.x), f2b(v.y), f2b(v.z), f2b(v.w));
  }
  for (int i = gtid; i < G_ * 512; i += NTHR) {   // [dec_Wih | dec_Whh]
    int n = i >> 9, k4 = (i & 511) * 4;
    const float* src = (k4 < 1024) ? (p.dec_Wih + (size_t)n * 1024 + k4)
                                   : (p.dec_Whh + (size_t)n * 1024 + (k4 - 1024));
    float4 v = *(const float4*)src;
    *(ushort4*)(p.wdecG + (size_t)n * 2048 + k4) = make_ushort4(f2b(v.x), f2b(v.y), f2b(v.z), f2b(v.w));
  }
  for (int i = gtid; i < S_ * B_ * 256; i += NTHR) {   // encoder embedding gather
    int m = i >> 8, k4 = (i & 255) * 4;
    float4 v = *(const float4*)(p.enc_emb + (size_t)p.input[m] * 1024 + k4);
    *(ushort4*)(p.Xbf + (size_t)m * 1024 + k4) = make_ushort4(f2b(v.x), f2b(v.y), f2b(v.z), f2b(v.w));
  }
  for (int i = gtid; i < T_ * B_ * 256; i += NTHR) {   // teacher-forced decoder x (relu)
    int m = i >> 8, k4 = (i & 255) * 4;
    int t = m >> 5, b = m & 31;
    int tok = (t == 0) ? 0 : p.target[(t - 1) * 32 + b];
    float4 v = *(const float4*)(p.dec_emb + (size_t)tok * 1024 + k4);
    *(ushort4*)(p.xball + (size_t)m * 1024 + k4) =
        make_ushort4(f2b(fmaxf(v.x, 0.f)), f2b(fmaxf(v.y, 0.f)),
                     f2b(fmaxf(v.z, 0.f)), f2b(fmaxf(v.w, 0.f)));
  }
  gbar(p.bar, ++bargen);

  // ---------- phase 1: batched GEMMs: encX (4096) | combX (1024) | scoreX (64) ----------
  for (int task = gwid; task < 4096 + 1024 + 64; task += NWAVE) {
    if (task < 4096) {
      int mt = task >> 6, ct = task & 63;
      wave_gemm<0>(p.Xbf + (size_t)mt * 32 * 1024, p.wencWih, 1024, 0, ct * 64,
                   nullptr, p.encXbf + (size_t)mt * 32 * G_, G_);
    } else if (task < 5120) {
      int tt = task - 4096, mt = tt >> 4, ct = tt & 15;
      wave_gemm<2>(p.xball + (size_t)mt * 32 * 1024, p.wcomb, 2048, 0, ct * 64,
                   nullptr, p.combX + (size_t)mt * 32 * 1024, 1024);
    } else {
      int mt = task - 5120;
      wave_gemm<3>(p.xball + (size_t)mt * 32 * 1024, p.wattn, 2048, 0, 0,
                   p.attn_b, p.scoreX + (size_t)mt * 32 * 64, 64);
    }
  }
  gbar(p.bar, ++bargen);

  // ---------- phase 2: encoder on blocks 64..127 with pinned encWhh ----------
  if (bid >= 64 && bid < 128)
    load_wpin_gates(p.wencWhh, 1024, 0, bid - 64, wpin);
  int pe = 0;
  for (int s = 0; s < 64; ++s) {
    if (bid >= 64 && bid < 128) {
      const int grp = bid - 64;
      const u16* hprev = p.hbuf + (size_t)pe * B_ * H_;
      u16* hnext = p.hbuf + (size_t)(pe ^ 1) * B_ * H_;
      grouped_gemm8_pinned(hprev, wpin, red_s, sg_s);
      {
        int slot = tid;
        int b = slot >> 4, jj = slot & 15, j = grp * 16 + jj;
        size_t xo = (size_t)(s * 32 + b) * G_;
        float g0 = sg_s[b * 64 + jj]      + b2f(p.encXbf[xo + j])        + p.enc_b[j];
        float g1 = sg_s[b * 64 + 16 + jj] + b2f(p.encXbf[xo + 1024 + j]) + p.enc_b[1024 + j];
        float g2 = sg_s[b * 64 + 32 + jj] + b2f(p.encXbf[xo + 2048 + j]) + p.enc_b[2048 + j];
        float g3 = sg_s[b * 64 + 48 + jj] + b2f(p.encXbf[xo + 3072 + j]) + p.enc_b[3072 + j];
        float ig = sigf(g0), fg = sigf(g1), gg = tanhf(g2), og = sigf(g3);
        float cn = fg * p.cbuf[b * 1024 + j] + ig * gg;
        float hn = og * tanhf(cn);
        p.cbuf[b * 1024 + j] = cn;
        u16 hb2 = f2b(hn);
        hnext[b * 1024 + j] = hb2;
        p.enc_bs[((size_t)b * 1024 + j) * 64 + s] = hb2;
      }
    }
    pe ^= 1;
    gbar(p.bar, ++bargen);
  }

  // ---------- phase 3: decoder ----------
  int pd = pe;   // == 0
  if (utf) {
    if (bid < 32)                      load_wpin_comb(p.wcomb, bid, wpin);
    else if (bid >= 64 && bid < 128)   load_wpin_gates(p.wdecG, 2048, 1024, bid - 64, wpin);
    else if (bid >= 128 && bid < 192)  load_wpin_gates(p.wdecG, 2048, 0, bid - 128, wpin);
    for (int t = 0; t < 64; ++t) {
      const u16* hprev = p.hbuf + (size_t)pd * B_ * H_;
      u16* hnext = p.hbuf + (size_t)(pd ^ 1) * B_ * H_;
      const bool batch = ((t & 7) == 0) && (t > 0);
      // ---- phase A: attention (0..31) || gatesH pinned (64..127)
      // ----          || batch logits part 1 on 160 idle blocks (32..63, 128..255) ----
      if (bid < 32) {
        float* hsh = red_s;            // 1024
        float* ssc = red_s + 1024;     // 512
        float* aw  = red_s + 1536;     // 64
        const int b = bid;
        {
          ushort2 hq = *(const ushort2*)(hprev + (size_t)b * 1024 + tid * 2);
          hsh[tid * 2] = b2f(hq.x);
          hsh[tid * 2 + 1] = b2f(hq.y);
        }
        __syncthreads();
        {
          const int sidx = tid & 63, q = tid >> 6;
          const u16* wr = p.wattn + (size_t)sidx * 2048 + 1024 + q * 128;
          const float* src = hsh + q * 128;
          float acc = 0.f;
          for (int k8 = 0; k8 < 16; ++k8) {
            bf16x8 v = *(const bf16x8*)(wr + k8 * 8);
#pragma unroll
            for (int e = 0; e < 8; ++e)
              acc = fmaf(src[k8 * 8 + e], b2f((u16)v[e]), acc);
          }
          ssc[q * 64 + sidx] = acc;
        }
        __syncthreads();
        if (tid < 64) {
          float sc = p.scoreX[(size_t)(t * 32 + b) * 64 + tid];
#pragma unroll
          for (int q = 0; q < 8; ++q) sc += ssc[q * 64 + tid];
          float m = sc;
#pragma unroll
          for (int off = 32; off; off >>= 1) m = fmaxf(m, __shfl_xor(m, off));
          float e = expf(sc - m), sum = e;
#pragma unroll
          for (int off = 32; off; off >>= 1) sum += __shfl_xor(sum, off);
          aw[tid] = e / sum;
        }
        __syncthreads();
        for (int j = tid; j < 1024; j += BT) {
          const u16* rowp = p.enc_bs + ((size_t)b * 1024 + j) * 64;
          float acc = 0.f;
#pragma unroll
          for (int s8 = 0; s8 < 8; ++s8) {
            bf16x8 v = *(const bf16x8*)(rowp + s8 * 8);
#pragma unroll
            for (int e = 0; e < 8; ++e)
              acc = fmaf(aw[s8 * 8 + e], b2f((u16)v[e]), acc);
          }
          p.vb[(size_t)b * 1024 + j] = f2b(acc);
        }
      } else if (bid >= 64 && bid < 128) {
        const int grp = bid - 64;
        grouped_gemm8_pinned(hprev, wpin, red_s, sg_s);
        {
          int slot = tid;
          int b = slot >> 4, jj = slot & 15, j = grp * 16 + jj;
          p.gatesH[(size_t)b * G_ + j]        = sg_s[b * 64 + jj];
          p.gatesH[(size_t)b * G_ + 1024 + j] = sg_s[b * 64 + 16 + jj];
          p.gatesH[(size_t)b * G_ + 2048 + j] = sg_s[b * 64 + 32 + jj];
          p.gatesH[(size_t)b * G_ + 3072 + j] = sg_s[b * 64 + 48 + jj];
        }
      } else if (batch) {
        // R14 change: batch logits part 1, tasks [0,2000), on 160 idle blocks
        const int lb = (bid < 64) ? (bid - 32) : (bid - 96);   // 0..31, 32..159
        const u16* Abase = p.hall + (size_t)(t - 8) * 32 * 1024;
        for (int task = lb * 8 + (tid >> 6); task < 2000; task += 160 * 8) {
          int ct = task >> 3, mt = task & 7;
          wave_gemm<1>(Abase + (size_t)mt * 32 * 1024, p.wout, 1024, 0, ct * 64,
                       p.out_b, p.ring + (size_t)mt * 32 * V_, V_);
        }
      }
      gbar(p.bar, ++bargen);
      // ---- phase B: comb-v pinned (0..31) || batch logits part 2 (32..255) ----
      if (bid < 32) {
        comb8_pinned(p, bid, t, wpin, red_s);
      } else if (batch) {
        const u16* Abase = p.hall + (size_t)(t - 8) * 32 * 1024;
        for (int task = 2000 + (bid - 32) * 8 + (tid >> 6); task < 4000; task += 224 * 8) {
          int ct = task >> 3, mt = task & 7;
          wave_gemm<1>(Abase + (size_t)mt * 32 * 1024, p.wout, 1024, 0, ct * 64,
                       p.out_b, p.ring + (size_t)mt * 32 * V_, V_);
        }
      }
      gbar(p.bar, ++bargen);
      // ---- phase C: gates-x pinned + LSTM (128..191) || batch loss (192..255) ----
      if (bid >= 128 && bid < 192) {
        const int grp = bid - 128;
        grouped_gemm8_pinned(p.nbuf, wpin, red_s, sg_s);
        {
          int slot = tid;
          int b = slot >> 4, jj = slot & 15, j = grp * 16 + jj;
          float g0 = sg_s[b * 64 + jj]      + p.gatesH[(size_t)b * G_ + j]        + p.dec_b[j];
          float g1 = sg_s[b * 64 + 16 + jj] + p.gatesH[(size_t)b * G_ + 1024 + j] + p.dec_b[1024 + j];
          float g2 = sg_s[b * 64 + 32 + jj] + p.gatesH[(size_t)b * G_ + 2048 + j] + p.dec_b[2048 + j];
          float g3 = sg_s[b * 64 + 48 + jj] + p.gatesH[(size_t)b * G_ + 3072 + j] + p.dec_b[3072 + j];
          float ig = sigf(g0), fg = sigf(g1), gg = tanhf(g2), og = sigf(g3);
          float cn = fg * p.cbuf[b * 1024 + j] + ig * gg;
          float hn = og * tanhf(cn);
          p.cbuf[b * 1024 + j] = cn;
          u16 hb2 = f2b(hn);
          hnext[b * 1024 + j] = hb2;
          p.hall[((size_t)t * 32 + b) * 1024 + j] = hb2;
        }
      } else if (bid >= 192 && batch) {
        int base = (bid - 192) * 4;
        for (int rr = 0; rr < 4; ++rr) {
          int m = base + rr, gm = (t - 8) * 32 + m;
          loss_row_bf16<false>(p.ring + (size_t)m * V_, p.target[gm], &p.loss_p[gm],
                               nullptr, red_s);
        }
      }
      gbar(p.bar, ++bargen);
      pd ^= 1;
    }
    // ---- E1: batched logits for h[56..63] on all 256 blocks ----
    {
      const u16* Abase = p.hall + (size_t)56 * 32 * 1024;
      for (int task = bid * 8 + (tid >> 6); task < 4000; task += 2048) {
        int ct = task >> 3, mt = task & 7;
        wave_gemm<1>(Abase + (size_t)mt * 32 * 1024, p.wout, 1024, 0, ct * 64,
                     p.out_b, p.ring + (size_t)mt * 32 * V_, V_);
      }
    }
    gbar(p.bar, ++bargen);
    // ---- E2: loss rows 1792..2047 on blocks 0..127 ----
    if (bid < 128) {
      for (int rr = 0; rr < 2; ++rr) {
        int m = bid * 2 + rr, gm = 56 * 32 + m;
        loss_row_bf16<false>(p.ring + (size_t)m * V_, p.target[gm], &p.loss_p[gm],
                             nullptr, red_s);
      }
    }
    gbar(p.bar, ++bargen);
  } else {
    // ---- tf=0: per-step feedback path (R10-identical) ----
    for (int t = 0; t < 64; ++t) {
      const u16* hprev = p.hbuf + (size_t)pd * B_ * H_;
      u16* hnext = p.hbuf + (size_t)(pd ^ 1) * B_ * H_;
      if (bid < 32) {
        float* xsh = red_s;
        float* hsh = red_s + 1024;
        float* ssc = red_s + 2048;
        float* aw  = red_s + 2560;
        const int b = bid;
        int tok = (t > 0) ? p.prevtok[b] : 0;
        {
          float2 v = *(const float2*)(p.dec_emb + (size_t)tok * 1024 + tid * 2);
          float x0 = fmaxf(v.x, 0.f), x1 = fmaxf(v.y, 0.f);
          xsh[tid * 2] = x0; xsh[tid * 2 + 1] = x1;
          *(ushort2*)(p.xb + (size_t)b * 1024 + tid * 2) = make_ushort2(f2b(x0), f2b(x1));
          ushort2 hq = *(const ushort2*)(hprev + (size_t)b * 1024 + tid * 2);
          hsh[tid * 2] = b2f(hq.x); hsh[tid * 2 + 1] = b2f(hq.y);
        }
        __syncthreads();
        {
          const int sidx = tid & 63, q = tid >> 6;
          const u16* wr = p.wattn + (size_t)sidx * 2048 + q * 256;
          const float* src = (q < 4) ? (xsh + q * 256) : (hsh + (q - 4) * 256);
          float acc = 0.f;
          for (int k8 = 0; k8 < 32; ++k8) {
            bf16x8 v = *(const bf16x8*)(wr + k8 * 8);
#pragma unroll
            for (int e = 0; e < 8; ++e)
              acc = fmaf(src[k8 * 8 + e], b2f((u16)v[e]), acc);
          }
          ssc[q * 64 + sidx] = acc;
        }
        __syncthreads();
        if (tid < 64) {
          float sc = p.attn_b[tid];
#pragma unroll
          for (int q = 0; q < 8; ++q) sc += ssc[q * 64 + tid];
          float m = sc;
#pragma unroll
          for (int off = 32; off; off >>= 1) m = fmaxf(m, __shfl_xor(m, off));
          float e = expf(sc - m), sum = e;
#pragma unroll
          for (int off = 32; off; off >>= 1) sum += __shfl_xor(sum, off);
          aw[tid] = e / sum;
        }
        __syncthreads();
        for (int j = tid; j < 1024; j += BT) {
          const u16* rowp = p.enc_bs + ((size_t)b * 1024 + j) * 64;
          float acc = 0.f;
#pragma unroll
          for (int s8 = 0; s8 < 8; ++s8) {
            bf16x8 v = *(const bf16x8*)(rowp + s8 * 8);
#pragma unroll
            for (int e = 0; e < 8; ++e)
              acc = fmaf(aw[s8 * 8 + e], b2f((u16)v[e]), acc);
          }
          p.vb[(size_t)b * 1024 + j] = f2b(acc);
        }
      } else if (bid >= 64 && bid < 128) {
        const int grp = bid - 64;
        grouped_gemm8(hprev, p.wdecG, 2048, 1024, grp, red_s, sg_s);
        {
          int slot = tid;
          int b = slot >> 4, jj = slot & 15, j = grp * 16 + jj;
          p.gatesH[(size_t)b * G_ + j]        = sg_s[b * 64 + jj];
          p.gatesH[(size_t)b * G_ + 1024 + j] = sg_s[b * 64 + 16 + jj];
          p.gatesH[(size_t)b * G_ + 2048 + j] = sg_s[b * 64 + 32 + jj];
          p.gatesH[(size_t)b * G_ + 3072 + j] = sg_s[b * 64 + 48 + jj];
        }
      }
      gbar(p.bar, ++bargen);
      if (bid < 32) comb8<2048, false>(p, bid, t, red_s);
      gbar(p.bar, ++bargen);
      if (bid < 64) {
        grouped_gemm8(p.nbuf, p.wdecG, 2048, 0, bid, red_s, sg_s);
        {
          int slot = tid;
          int b = slot >> 4, jj = slot & 15, j = bid * 16 + jj;
          float g0 = sg_s[b * 64 + jj]      + p.gatesH[(size_t)b * G_ + j]        + p.dec_b[j];
          float g1 = sg_s[b * 64 + 16 + jj] + p.gatesH[(size_t)b * G_ + 1024 + j] + p.dec_b[1024 + j];
          float g2 = sg_s[b * 64 + 32 + jj] + p.gatesH[(size_t)b * G_ + 2048 + j] + p.dec_b[2048 + j];
          float g3 = sg_s[b * 64 + 48 + jj] + p.gatesH[(size_t)b * G_ + 3072 + j] + p.dec_b[3072 + j];
          float ig = sigf(g0), fg = sigf(g1), gg = tanhf(g2), og = sigf(g3);
          float cn = fg * p.cbuf[b * 1024 + j] + ig * gg;
          float hn = og * tanhf(cn);
          p.cbuf[b * 1024 + j] = cn;
          u16 hb2 = f2b(hn);
          hnext[b * 1024 + j] = hb2;
          p.hall[((size_t)t * 32 + b) * 1024 + j] = hb2;
        }
      }
      gbar(p.bar, ++bargen);
      pd ^= 1;
      for (int task = gwid; task < 500; task += NWAVE)
        wave_gemm<1>(p.hbuf + (size_t)pd * B_ * H_, p.wout, 1024, 0, task * 64,
                     p.out_b, p.ring, V_);
      gbar(p.bar, ++bargen);
      if (bid < 32)
        loss_row_bf16<true>(p.ring + (size_t)bid * V_, p.target[t * 32 + bid],
                            &p.loss_p[t * 32 + bid], &p.prevtok[bid], red_s);
      gbar(p.bar, ++bargen);
    }
  }

  // ---------- final sum ----------
  if (bid == 0) {
    float a = 0.f;
    for (int i = tid; i < T_ * B_; i += BT) a += p.loss_p[i];
    red_s[tid] = a;
    __syncthreads();
    for (int off = 256; off; off >>= 1) {
      if (tid < off) red_s[tid] += red_s[tid + off];
      __syncthreads();
    }
    if (tid == 0) p.out[0] = red_s[0];
  }
}

// ---------------- host launch ----------------
extern "C" void kernel_launch(void* const* d_in, const int* in_sizes, int n_in,
                              void* d_out, int out_size, void* d_ws, size_t ws_size,
                              hipStream_t stream) {
  (void)in_sizes; (void)n_in; (void)out_size; (void)ws_size;
  Params p;
  p.input   = (const int*)d_in[0];
  p.target  = (const int*)d_in[1];
  p.use_tf  = (const int*)d_in[2];
  p.enc_emb = (const float*)d_in[3];
  p.enc_Wih = (const float*)d_in[4];
  p.enc_Whh = (const float*)d_in[5];
  p.enc_b   = (const float*)d_in[6];
  p.dec_emb = (const float*)d_in[7];
  p.dec_Wih = (const float*)d_in[8];
  p.dec_Whh = (const float*)d_in[9];
  p.dec_b   = (const float*)d_in[10];
  p.attn_W  = (const float*)d_in[11];
  p.attn_b  = (const float*)d_in[12];
  p.comb_W  = (const float*)d_in[13];
  p.comb_b  = (const float*)d_in[14];
  p.out_W   = (const float*)d_in[15];
  p.out_b   = (const float*)d_in[16];
  p.out     = (float*)d_out;

  char* ws = (char*)d_ws;
  size_t off = 0;
  auto alloc = [&](size_t bytes) {
    void* q = ws + off;
    off += ((bytes + 255) & ~(size_t)255);
    return q;
  };
  p.Xbf     = (u16*)alloc((size_t)S_ * B_ * H_ * 2);       // 4.2 MB
  p.encXbf  = (u16*)alloc((size_t)S_ * B_ * G_ * 2);       // 16.8 MB (ring aliases after encoder)
  p.enc_bs  = (u16*)alloc((size_t)B_ * H_ * S_ * 2);       // 4.2 MB
  p.hall    = (u16*)alloc((size_t)T_ * B_ * H_ * 2);       // 4.2 MB
  p.hbuf    = (u16*)alloc((size_t)2 * B_ * H_ * 2);
  p.xb      = (u16*)alloc((size_t)B_ * H_ * 2);
  p.vb      = (u16*)alloc((size_t)B_ * H_ * 2);
  p.nbuf    = (u16*)alloc((size_t)B_ * H_ * 2);
  p.xball   = (u16*)alloc((size_t)T_ * B_ * H_ * 2);       // 4.2 MB
  p.combX   = (float*)alloc((size_t)T_ * B_ * H_ * 4);     // 8.4 MB
  p.scoreX  = (float*)alloc((size_t)T_ * B_ * 64 * 4);     // 0.5 MB
  p.gatesH  = (float*)alloc((size_t)B_ * G_ * 4);          // 0.5 MB
  p.cbuf    = (float*)alloc((size_t)B_ * H_ * 4);
  p.loss_p  = (float*)alloc((size_t)T_ * B_ * 4);
  p.prevtok = (int*)alloc(B_ * 4);
  p.bar     = (unsigned*)alloc(1024);
  p.wencWih = (u16*)alloc((size_t)G_ * H_ * 2);            // 8.4 MB
  p.wencWhh = (u16*)alloc((size_t)G_ * H_ * 2);            // 8.4 MB
  p.wdecG   = (u16*)alloc((size_t)G_ * 2 * H_ * 2);        // 16.8 MB
  p.wcomb   = (u16*)alloc((size_t)H_ * 2 * H_ * 2);        // 4.2 MB
  p.wattn   = (u16*)alloc((size_t)S_ * 2 * H_ * 2);        // 0.26 MB
  p.wout    = (u16*)alloc((size_t)V_ * H_ * 2);            // 65.5 MB
  // logits ring: 256 rows x 32000 bf16 = 16.38 MB, aliases dead-after-encoder encXbf
  p.ring = p.encXbf;
  // total ~147 MB

  binit<<<1, 288, 0, stream>>>(p.bar);
  seq2seq_all<<<NB, BT, 0, stream>>>(p);
}

// Round 15
// 5769.720 us; speedup vs baseline: 4.6412x; 1.0076x over previous
//
#include <hip/hip_runtime.h>
#include <cmath>
#include <cstddef>

// S=T=64, B=32, H=1024, G=4H, V=32000
constexpr int S_ = 64, T_ = 64, B_ = 32, H_ = 1024, G_ = 4096, V_ = 32000;
constexpr int NB = 256, BT = 512, NTHR = NB * BT, NWAVE = NB * 8;

typedef unsigned short u16;   // bf16 bit pattern
typedef __attribute__((ext_vector_type(8))) short bf16x8;
typedef __attribute__((ext_vector_type(4))) float f32x4;

__device__ __forceinline__ float sigf(float x) { return 1.f / (1.f + expf(-x)); }
__device__ __forceinline__ float b2f(u16 u) { return __uint_as_float(((unsigned)u) << 16); }
__device__ __forceinline__ u16 f2b(float f) {
  unsigned u = __float_as_uint(f);
  return (u16)((u + 0x7fff + ((u >> 16) & 1)) >> 16);  // RNE
}
__device__ __forceinline__ f32x4 mfma16(bf16x8 a, bf16x8 b, f32x4 c) {
  return __builtin_amdgcn_mfma_f32_16x16x32_bf16(a, b, c, 0, 0, 0);
}

struct Params {
  const int *input, *target, *use_tf;
  const float *enc_emb, *enc_Wih, *enc_Whh, *enc_b;
  const float *dec_emb, *dec_Wih, *dec_Whh, *dec_b;
  const float *attn_W, *attn_b, *comb_W, *comb_b, *out_W, *out_b;
  float* out;
  u16 *Xbf, *encXbf, *enc_bs, *hall, *hbuf, *xb, *vb, *nbuf, *xball, *ring;
  float *combX, *scoreX, *gatesH, *cbuf, *loss_p;
  int* prevtok;
  u16 *wencWih, *wencWhh, *wdecG, *wcomb, *wattn, *wout;
  unsigned* bar;
};

// ---------- two-level device-scope grid barrier ----------
__device__ __forceinline__ void gbar(unsigned* bar, unsigned target) {
  __syncthreads();
  if (threadIdx.x == 0) {
    __threadfence();
    int g = blockIdx.x >> 4;
    unsigned a = __hip_atomic_fetch_add(bar + g * 16, 1u, __ATOMIC_ACQ_REL,
                                        __HIP_MEMORY_SCOPE_AGENT);
    if (a == 15u) {
      unsigned r = __hip_atomic_fetch_add(bar + 256, 1u, __ATOMIC_ACQ_REL,
                                          __HIP_MEMORY_SCOPE_AGENT);
      if (r == 15u) {
        for (int i = 0; i < 16; ++i)
          __hip_atomic_store(bar + i * 16, 0u, __ATOMIC_RELAXED, __HIP_MEMORY_SCOPE_AGENT);
        __hip_atomic_store(bar + 256, 0u, __ATOMIC_RELAXED, __HIP_MEMORY_SCOPE_AGENT);
        __hip_atomic_store(bar + 272, target, __ATOMIC_RELEASE, __HIP_MEMORY_SCOPE_AGENT);
      }
    }
    while (__hip_atomic_load(bar + 272, __ATOMIC_ACQUIRE, __HIP_MEMORY_SCOPE_AGENT) < target)
      __builtin_amdgcn_s_sleep(2);
  }
  __syncthreads();
}

// ---------- per-wave 32x64 tile GEMM, K=1024 ----------
// EPI: 0 bf16, 1 bf16+bias, 2 f32, 3 f32+bias
template <int EPI>
__device__ void wave_gemm(const u16* __restrict__ A, const u16* __restrict__ W,
                          int ldw, int wkoff, int colbase, const float* __restrict__ bias,
                          void* __restrict__ outp, int ldo) {
  const int lane = threadIdx.x & 63;
  const int r = lane & 15, kg = (lane >> 4) * 8;
  const u16* Ar = A + (size_t)r * 1024 + kg;
  const u16* Wr = W + (size_t)(colbase + r) * ldw + wkoff + kg;
  f32x4 acc[2][4] = {};
#pragma unroll 2
  for (int k0 = 0; k0 < 1024; k0 += 32) {
    bf16x8 a0 = *(const bf16x8*)(Ar + k0);
    bf16x8 a1 = *(const bf16x8*)(Ar + 16 * 1024 + k0);
    bf16x8 b0 = *(const bf16x8*)(Wr + k0);
    bf16x8 b1 = *(const bf16x8*)(Wr + (size_t)16 * ldw + k0);
    bf16x8 b2 = *(const bf16x8*)(Wr + (size_t)32 * ldw + k0);
    bf16x8 b3 = *(const bf16x8*)(Wr + (size_t)48 * ldw + k0);
    acc[0][0] = mfma16(a0, b0, acc[0][0]);
    acc[1][0] = mfma16(a1, b0, acc[1][0]);
    acc[0][1] = mfma16(a0, b1, acc[0][1]);
    acc[1][1] = mfma16(a1, b1, acc[1][1]);
    acc[0][2] = mfma16(a0, b2, acc[0][2]);
    acc[1][2] = mfma16(a1, b2, acc[1][2]);
    acc[0][3] = mfma16(a0, b3, acc[0][3]);
    acc[1][3] = mfma16(a1, b3, acc[1][3]);
  }
#pragma unroll
  for (int mi = 0; mi < 2; ++mi)
#pragma unroll
    for (int nj = 0; nj < 4; ++nj) {
      int col = colbase + nj * 16 + (lane & 15);
      int row0 = mi * 16 + ((lane >> 4) << 2);
#pragma unroll
      for (int reg = 0; reg < 4; ++reg) {
        float v = acc[mi][nj][reg];
        if (EPI == 1 || EPI == 3) v += bias[col];
        if (EPI <= 1) ((u16*)outp)[(size_t)(row0 + reg) * ldo + col] = f2b(v);
        else ((float*)outp)[(size_t)(row0 + reg) * ldo + col] = v;
      }
    }
}

// ---------- streamed block 32x64 grouped-col GEMM (tf=0 path) ----------
__device__ void grouped_gemm8(const u16* __restrict__ A, const u16* __restrict__ Wm,
                              int ldw, int wkoff, int grp, float* red, float* sg) {
  const int tid = threadIdx.x, w = tid >> 6, lane = tid & 63;
  const int r = lane & 15, kg = (lane >> 4) * 8;
  const int kw0 = w * 128;
  const u16* Ar = A + (size_t)r * 1024 + kw0 + kg;
  const u16* W0 = Wm + (size_t)(grp * 16 + r) * ldw + wkoff + kw0 + kg;
  const u16* W1 = W0 + (size_t)1024 * ldw;
  const u16* W2 = W0 + (size_t)2048 * ldw;
  const u16* W3 = W0 + (size_t)3072 * ldw;
  f32x4 acc[2][4] = {};
#pragma unroll
  for (int k0 = 0; k0 < 128; k0 += 32) {
    bf16x8 a0 = *(const bf16x8*)(Ar + k0);
    bf16x8 a1 = *(const bf16x8*)(Ar + 16 * 1024 + k0);
    bf16x8 b0 = *(const bf16x8*)(W0 + k0);
    bf16x8 b1 = *(const bf16x8*)(W1 + k0);
    bf16x8 b2 = *(const bf16x8*)(W2 + k0);
    bf16x8 b3 = *(const bf16x8*)(W3 + k0);
    acc[0][0] = mfma16(a0, b0, acc[0][0]);
    acc[1][0] = mfma16(a1, b0, acc[1][0]);
    acc[0][1] = mfma16(a0, b1, acc[0][1]);
    acc[1][1] = mfma16(a1, b1, acc[1][1]);
    acc[0][2] = mfma16(a0, b2, acc[0][2]);
    acc[1][2] = mfma16(a1, b2, acc[1][2]);
    acc[0][3] = mfma16(a0, b3, acc[0][3]);
    acc[1][3] = mfma16(a1, b3, acc[1][3]);
  }
#pragma unroll
  for (int mi = 0; mi < 2; ++mi)
#pragma unroll
    for (int nj = 0; nj < 4; ++nj)
#pragma unroll
      for (int reg = 0; reg < 4; ++reg)
        red[(((w * 8) + mi * 4 + nj) * 64 + lane) * 4 + reg] = acc[mi][nj][reg];
  __syncthreads();
  {
    const int p2 = w;
    const int mi = p2 >> 2, nj = p2 & 3;
#pragma unroll
    for (int reg = 0; reg < 4; ++reg) {
      float v = 0.f;
#pragma unroll
      for (int ww = 0; ww < 8; ++ww)
        v += red[(((ww * 8) + p2) * 64 + lane) * 4 + reg];
      sg[(mi * 16 + ((lane >> 4) << 2) + reg) * 64 + nj * 16 + (lane & 15)] = v;
    }
  }
  __syncthreads();
}

// ---------- pinned-weight loaders: 16 frags = 64 VGPR/thread ----------
__device__ __forceinline__ void load_wpin_gates(const u16* Wm, int ldw, int wkoff,
                                                int grp, bf16x8* wp) {
  const int w = threadIdx.x >> 6, lane = threadIdx.x & 63;
  const int r = lane & 15, kg = (lane >> 4) * 8;
  const int kw0 = w * 128;
  const u16* W0 = Wm + (size_t)(grp * 16 + r) * ldw + wkoff + kw0 + kg;
#pragma unroll
  for (int q = 0; q < 4; ++q)
#pragma unroll
    for (int ks = 0; ks < 4; ++ks)
      wp[q * 4 + ks] = *(const bf16x8*)(W0 + (size_t)(q * 1024) * ldw + ks * 32);
}

__device__ __forceinline__ void load_wpin_comb(const u16* Wm, int cb, bf16x8* wp) {
  const int w = threadIdx.x >> 6, lane = threadIdx.x & 63;
  const int r = lane & 15, kg = (lane >> 4) * 8;
  const int kw0 = w * 128;
  const u16* W0 = Wm + (size_t)(cb * 32 + r) * 2048 + 1024 + kw0 + kg;
#pragma unroll
  for (int h = 0; h < 2; ++h)
#pragma unroll
    for (int ks = 0; ks < 4; ++ks)
      wp[h * 4 + ks] = *(const bf16x8*)(W0 + (size_t)(h * 16) * 2048 + ks * 32);
}

// ---------- pinned grouped-col GEMM -> sg[32][64] ----------
__device__ void grouped_gemm8_pinned(const u16* __restrict__ A, const bf16x8* wp,
                                     float* red, float* sg) {
  const int tid = threadIdx.x, w = tid >> 6, lane = tid & 63;
  const int r = lane & 15, kg = (lane >> 4) * 8;
  const int kw0 = w * 128;
  const u16* Ar = A + (size_t)r * 1024 + kw0 + kg;
  f32x4 acc[2][4] = {};
#pragma unroll
  for (int ks = 0; ks < 4; ++ks) {
    bf16x8 a0 = *(const bf16x8*)(Ar + ks * 32);
    bf16x8 a1 = *(const bf16x8*)(Ar + 16 * 1024 + ks * 32);
    acc[0][0] = mfma16(a0, wp[0 + ks], acc[0][0]);
    acc[1][0] = mfma16(a1, wp[0 + ks], acc[1][0]);
    acc[0][1] = mfma16(a0, wp[4 + ks], acc[0][1]);
    acc[1][1] = mfma16(a1, wp[4 + ks], acc[1][1]);
    acc[0][2] = mfma16(a0, wp[8 + ks], acc[0][2]);
    acc[1][2] = mfma16(a1, wp[8 + ks], acc[1][2]);
    acc[0][3] = mfma16(a0, wp[12 + ks], acc[0][3]);
    acc[1][3] = mfma16(a1, wp[12 + ks], acc[1][3]);
  }
#pragma unroll
  for (int mi = 0; mi < 2; ++mi)
#pragma unroll
    for (int nj = 0; nj < 4; ++nj)
#pragma unroll
      for (int reg = 0; reg < 4; ++reg)
        red[(((w * 8) + mi * 4 + nj) * 64 + lane) * 4 + reg] = acc[mi][nj][reg];
  __syncthreads();
  {
    const int p2 = w;
    const int mi = p2 >> 2, nj = p2 & 3;
#pragma unroll
    for (int reg = 0; reg < 4; ++reg) {
      float v = 0.f;
#pragma unroll
      for (int ww = 0; ww < 8; ++ww)
        v += red[(((ww * 8) + p2) * 64 + lane) * 4 + reg];
      sg[(mi * 16 + ((lane >> 4) << 2) + reg) * 64 + nj * 16 + (lane & 15)] = v;
    }
  }
  __syncthreads();
}

// ---------- streamed comb (tf=0): K=2048 over [xb|vb] ----------
template <int KTOT, bool HASX>
__device__ void comb8(const Params& p, int cb, int t, float* red) {
  const int tid = threadIdx.x, w = tid >> 6, lane = tid & 63;
  const int r = lane & 15, kg = (lane >> 4) * 8;
  constexpr int KSW = KTOT / 8;
  const int kw0 = w * KSW;
  const u16* Abase;
  int koff;
  if (KTOT == 2048) { Abase = (kw0 < 1024) ? p.xb : p.vb; koff = kw0 & 1023; }
  else { Abase = p.vb; koff = kw0; }
  const u16* Ar = Abase + (size_t)r * 1024 + koff + kg;
  const int wko = (KTOT == 1024) ? 1024 : 0;
  const u16* W0 = p.wcomb + (size_t)(cb * 32 + r) * 2048 + wko + kw0 + kg;
  const u16* W1 = W0 + (size_t)16 * 2048;
  f32x4 acc[2][2] = {};
#pragma unroll
  for (int k0 = 0; k0 < KSW; k0 += 32) {
    bf16x8 a0 = *(const bf16x8*)(Ar + k0);
    bf16x8 a1 = *(const bf16x8*)(Ar + 16 * 1024 + k0);
    bf16x8 b0 = *(const bf16x8*)(W0 + k0);
    bf16x8 b1 = *(const bf16x8*)(W1 + k0);
    acc[0][0] = mfma16(a0, b0, acc[0][0]);
    acc[1][0] = mfma16(a1, b0, acc[1][0]);
    acc[0][1] = mfma16(a0, b1, acc[0][1]);
    acc[1][1] = mfma16(a1, b1, acc[1][1]);
  }
#pragma unroll
  for (int mi = 0; mi < 2; ++mi)
#pragma unroll
    for (int nj = 0; nj < 2; ++nj)
#pragma unroll
      for (int reg = 0; reg < 4; ++reg)
        red[(((w * 4) + mi * 2 + nj) * 64 + lane) * 4 + reg] = acc[mi][nj][reg];
  __syncthreads();
  if (w < 4) {
    const int p2 = w, mi = p2 >> 1, nj = p2 & 1;
#pragma unroll
    for (int reg = 0; reg < 4; ++reg) {
      float v = 0.f;
#pragma unroll
      for (int ww = 0; ww < 8; ++ww)
        v += red[(((ww * 4) + p2) * 64 + lane) * 4 + reg];
      int row = mi * 16 + ((lane >> 4) << 2) + reg;
      int col = cb * 32 + nj * 16 + (lane & 15);
      if (HASX) v += p.combX[(size_t)(t * 32 + row) * 1024 + col];
      v += p.comb_b[col];
      p.nbuf[(size_t)row * 1024 + col] = f2b(fmaxf(v, 0.f));
    }
  }
  __syncthreads();
}

// ---------- pinned comb (tf=1): v-half K=1024 + combX + bias, relu -> nbuf ----------
__device__ void comb8_pinned(const Params& p, int cb, int t, const bf16x8* wp, float* red) {
  const int tid = threadIdx.x, w = tid >> 6, lane = tid & 63;
  const int r = lane & 15, kg = (lane >> 4) * 8;
  const int kw0 = w * 128;
  const u16* Ar = p.vb + (size_t)r * 1024 + kw0 + kg;
  f32x4 acc[2][2] = {};
#pragma unroll
  for (int ks = 0; ks < 4; ++ks) {
    bf16x8 a0 = *(const bf16x8*)(Ar + ks * 32);
    bf16x8 a1 = *(const bf16x8*)(Ar + 16 * 1024 + ks * 32);
    acc[0][0] = mfma16(a0, wp[0 + ks], acc[0][0]);
    acc[1][0] = mfma16(a1, wp[0 + ks], acc[1][0]);
    acc[0][1] = mfma16(a0, wp[4 + ks], acc[0][1]);
    acc[1][1] = mfma16(a1, wp[4 + ks], acc[1][1]);
  }
#pragma unroll
  for (int mi = 0; mi < 2; ++mi)
#pragma unroll
    for (int nj = 0; nj < 2; ++nj)
#pragma unroll
      for (int reg = 0; reg < 4; ++reg)
        red[(((w * 4) + mi * 2 + nj) * 64 + lane) * 4 + reg] = acc[mi][nj][reg];
  __syncthreads();
  if (w < 4) {
    const int p2 = w, mi = p2 >> 1, nj = p2 & 1;
#pragma unroll
    for (int reg = 0; reg < 4; ++reg) {
      float v = 0.f;
#pragma unroll
      for (int ww = 0; ww < 8; ++ww)
        v += red[(((ww * 4) + p2) * 64 + lane) * 4 + reg];
      int row = mi * 16 + ((lane >> 4) << 2) + reg;
      int col = cb * 32 + nj * 16 + (lane & 15);
      v += p.combX[(size_t)(t * 32 + row) * 1024 + col] + p.comb_b[col];
      p.nbuf[(size_t)row * 1024 + col] = f2b(fmaxf(v, 0.f));
    }
  }
  __syncthreads();
}

// ---------- log-softmax loss over one bf16 logits row (512 threads) ----------
template <bool AM>
__device__ void loss_row_bf16(const u16* __restrict__ row, int tgt,
                              float* __restrict__ loss_out, int* __restrict__ am_out,
                              float* sh) {
  float* sm = sh;
  float* ss = sh + 512;
  float* sbv = sh + 1024;
  int* sbi = (int*)(sh + 1536);
  const int tid = threadIdx.x;
  float m = -INFINITY, ssum = 0.f, bestv = -INFINITY;
  int besti = 0x7fffffff;
  for (int v = tid; v < V_; v += BT) {
    float x = b2f(row[v]);
    if (x > m) { ssum = ssum * expf(m - x) + 1.f; m = x; }
    else ssum += expf(x - m);
    if (AM) { if (x > bestv) { bestv = x; besti = v; } }
  }
  sm[tid] = m; ss[tid] = ssum;
  if (AM) { sbv[tid] = bestv; sbi[tid] = besti; }
  __syncthreads();
  for (int off = 256; off; off >>= 1) {
    if (tid < off) {
      float m2 = sm[tid + off], s2 = ss[tid + off];
      float mn = fmaxf(sm[tid], m2);
      ss[tid] = ss[tid] * expf(sm[tid] - mn) + s2 * expf(m2 - mn);
      sm[tid] = mn;
      if (AM) {
        float bv2 = sbv[tid + off];
        int bi2 = sbi[tid + off];
        if (bv2 > sbv[tid] || (bv2 == sbv[tid] && bi2 < sbi[tid])) { sbv[tid] = bv2; sbi[tid] = bi2; }
      }
    }
    __syncthreads();
  }
  if (tid == 0) {
    float lp = b2f(row[tgt]) - (sm[0] + logf(ss[0]));
    *loss_out = -lp * (1.f / 32.f);
    if (AM) *am_out = sbi[0];
  }
  __syncthreads();
}

// =================== main persistent kernel ===================
__global__ void binit(unsigned* bar) {
  int i = threadIdx.x;
  if (i < 288) bar[i] = 0u;
}

__global__ __launch_bounds__(BT, 2) void seq2seq_all(Params p) {
  __shared__ float red_s[16384];   // 64 KB
  __shared__ float sg_s[2048];     // 8 KB
  unsigned bargen = 0;
  const int tid = threadIdx.x, bid = blockIdx.x;
  const int gtid = bid * BT + tid;
  const int gwid = bid * 8 + (tid >> 6);
  const int utf = p.use_tf[0];
  bf16x8 wpin[16];

  // ---------- phase 0: zero state + all weight conversions + gathers ----------
  for (int i = gtid; i < B_ * H_; i += NTHR) { p.cbuf[i] = 0.f; p.hbuf[i] = 0; }
  for (int i = gtid; i < G_ * H_ / 4; i += NTHR) {
    float4 v = *(const float4*)(p.enc_Wih + (size_t)i * 4);
    *(ushort4*)(p.wencWih + (size_t)i * 4) = make_ushort4(f2b(v.x), f2b(v.y), f2b(v.z), f2b(v.w));
  }
  for (int i = gtid; i < G_ * H_ / 4; i += NTHR) {
    float4 v = *(const float4*)(p.enc_Whh + (size_t)i * 4);
    *(ushort4*)(p.wencWhh + (size_t)i * 4) = make_ushort4(f2b(v.x), f2b(v.y), f2b(v.z), f2b(v.w));
  }
  for (int i = gtid; i < 2 * H_ * H_ / 4; i += NTHR) {
    float4 v = *(const float4*)(p.comb_W + (size_t)i * 4);
    *(ushort4*)(p.wcomb + (size_t)i * 4) = make_ushort4(f2b(v.x), f2b(v.y), f2b(v.z), f2b(v.w));
  }
  for (int i = gtid; i < S_ * 2 * H_ / 4; i += NTHR) {
    float4 v = *(const float4*)(p.attn_W + (size_t)i * 4);
    *(ushort4*)(p.wattn + (size_t)i * 4) = make_ushort4(f2b(v.x), f2b(v.y), f2b(v.z), f2b(v.w));
  }
  for (int i = gtid; i < V_ * H_ / 4; i += NTHR) {
    float4 v = *(const float4*)(p.out_W + (size_t)i * 4);
    *(ushort4*)(p.wout + (size_t)i * 4) = make_ushort4(f2b(v.x), f2b(v.y), f2b(v.z), f2b(v.w));
  }
  for (int i = gtid; i < G_ * 512; i += NTHR) {   // [dec_Wih | dec_Whh]
    int n = i >> 9, k4 = (i & 511) * 4;
    const float* src = (k4 < 1024) ? (p.dec_Wih + (size_t)n * 1024 + k4)
                                   : (p.dec_Whh + (size_t)n * 1024 + (k4 - 1024));
    float4 v = *(const float4*)src;
    *(ushort4*)(p.wdecG + (size_t)n * 2048 + k4) = make_ushort4(f2b(v.x), f2b(v.y), f2b(v.z), f2b(v.w));
  }
  for (int i = gtid; i < S_ * B_ * 256; i += NTHR) {   // encoder embedding gather
    int m = i >> 8, k4 = (i & 255) * 4;
    float4 v = *(const float4*)(p.enc_emb + (size_t)p.input[m] * 1024 + k4);
    *(ushort4*)(p.Xbf + (size_t)m * 1024 + k4) = make_ushort4(f2b(v.x), f2b(v.y), f2b(v.z), f2b(v.w));
  }
  for (int i = gtid; i < T_ * B_ * 256; i += NTHR) {   // teacher-forced decoder x (relu)
    int m = i >> 8, k4 = (i & 255) * 4;
    int t = m >> 5, b = m & 31;
    int tok = (t == 0) ? 0 : p.target[(t - 1) * 32 + b];
    float4 v = *(const float4*)(p.dec_emb + (size_t)tok * 1024 + k4);
    *(ushort4*)(p.xball + (size_t)m * 1024 + k4) =
        make_ushort4(f2b(fmaxf(v.x, 0.f)), f2b(fmaxf(v.y, 0.f)),
                     f2b(fmaxf(v.z, 0.f)), f2b(fmaxf(v.w, 0.f)));
  }
  gbar(p.bar, ++bargen);

  // ---------- phase 1: batched GEMMs: encX (4096) | combX (1024) | scoreX (64) ----------
  for (int task = gwid; task < 4096 + 1024 + 64; task += NWAVE) {
    if (task < 4096) {
      int mt = task >> 6, ct = task & 63;
      wave_gemm<0>(p.Xbf + (size_t)mt * 32 * 1024, p.wencWih, 1024, 0, ct * 64,
                   nullptr, p.encXbf + (size_t)mt * 32 * G_, G_);
    } else if (task < 5120) {
      int tt = task - 4096, mt = tt >> 4, ct = tt & 15;
      wave_gemm<2>(p.xball + (size_t)mt * 32 * 1024, p.wcomb, 2048, 0, ct * 64,
                   nullptr, p.combX + (size_t)mt * 32 * 1024, 1024);
    } else {
      int mt = task - 5120;
      wave_gemm<3>(p.xball + (size_t)mt * 32 * 1024, p.wattn, 2048, 0, 0,
                   p.attn_b, p.scoreX + (size_t)mt * 32 * 64, 64);
    }
  }
  gbar(p.bar, ++bargen);

  // ---------- phase 2: encoder on blocks 64..127 with pinned encWhh ----------
  if (bid >= 64 && bid < 128)
    load_wpin_gates(p.wencWhh, 1024, 0, bid - 64, wpin);
  int pe = 0;
  for (int s = 0; s < 64; ++s) {
    if (bid >= 64 && bid < 128) {
      const int grp = bid - 64;
      const u16* hprev = p.hbuf + (size_t)pe * B_ * H_;
      u16* hnext = p.hbuf + (size_t)(pe ^ 1) * B_ * H_;
      grouped_gemm8_pinned(hprev, wpin, red_s, sg_s);
      {
        int slot = tid;
        int b = slot >> 4, jj = slot & 15, j = grp * 16 + jj;
        size_t xo = (size_t)(s * 32 + b) * G_;
        float g0 = sg_s[b * 64 + jj]      + b2f(p.encXbf[xo + j])        + p.enc_b[j];
        float g1 = sg_s[b * 64 + 16 + jj] + b2f(p.encXbf[xo + 1024 + j]) + p.enc_b[1024 + j];
        float g2 = sg_s[b * 64 + 32 + jj] + b2f(p.encXbf[xo + 2048 + j]) + p.enc_b[2048 + j];
        float g3 = sg_s[b * 64 + 48 + jj] + b2f(p.encXbf[xo + 3072 + j]) + p.enc_b[3072 + j];
        float ig = sigf(g0), fg = sigf(g1), gg = tanhf(g2), og = sigf(g3);
        float cn = fg * p.cbuf[b * 1024 + j] + ig * gg;
        float hn = og * tanhf(cn);
        p.cbuf[b * 1024 + j] = cn;
        u16 hb2 = f2b(hn);
        hnext[b * 1024 + j] = hb2;
        p.enc_bs[((size_t)b * 1024 + j) * 64 + s] = hb2;
      }
    }
    pe ^= 1;
    gbar(p.bar, ++bargen);
  }

  // ---------- phase 3: decoder ----------
  int pd = pe;   // == 0
  if (utf) {
    if (bid < 32)                      load_wpin_comb(p.wcomb, bid, wpin);
    else if (bid >= 64 && bid < 128)   load_wpin_gates(p.wdecG, 2048, 1024, bid - 64, wpin);
    else if (bid >= 128 && bid < 192)  load_wpin_gates(p.wdecG, 2048, 0, bid - 128, wpin);
    for (int t = 0; t < 64; ++t) {
      const u16* hprev = p.hbuf + (size_t)pd * B_ * H_;
      u16* hnext = p.hbuf + (size_t)(pd ^ 1) * B_ * H_;
      const bool batch = ((t & 7) == 0) && (t > 0);
      // ---- phase A: attention h-part (0..31) || gatesH pinned (64..127) ----
      if (bid < 32) {
        float* hsh = red_s;            // 1024
        float* ssc = red_s + 1024;     // 512
        float* aw  = red_s + 1536;     // 64
        const int b = bid;
        {
          ushort2 hq = *(const ushort2*)(hprev + (size_t)b * 1024 + tid * 2);
          hsh[tid * 2] = b2f(hq.x);
          hsh[tid * 2 + 1] = b2f(hq.y);
        }
        __syncthreads();
        {
          const int sidx = tid & 63, q = tid >> 6;
          const u16* wr = p.wattn + (size_t)sidx * 2048 + 1024 + q * 128;
          const float* src = hsh + q * 128;
          float acc = 0.f;
          for (int k8 = 0; k8 < 16; ++k8) {
            bf16x8 v = *(const bf16x8*)(wr + k8 * 8);
#pragma unroll
            for (int e = 0; e < 8; ++e)
              acc = fmaf(src[k8 * 8 + e], b2f((u16)v[e]), acc);
          }
          ssc[q * 64 + sidx] = acc;
        }
        __syncthreads();
        if (tid < 64) {
          float sc = p.scoreX[(size_t)(t * 32 + b) * 64 + tid];
#pragma unroll
          for (int q = 0; q < 8; ++q) sc += ssc[q * 64 + tid];
          float m = sc;
#pragma unroll
          for (int off = 32; off; off >>= 1) m = fmaxf(m, __shfl_xor(m, off));
          float e = expf(sc - m), sum = e;
#pragma unroll
          for (int off = 32; off; off >>= 1) sum += __shfl_xor(sum, off);
          aw[tid] = e / sum;
        }
        __syncthreads();
        for (int j = tid; j < 1024; j += BT) {
          const u16* rowp = p.enc_bs + ((size_t)b * 1024 + j) * 64;
          float acc = 0.f;
#pragma unroll
          for (int s8 = 0; s8 < 8; ++s8) {
            bf16x8 v = *(const bf16x8*)(rowp + s8 * 8);
#pragma unroll
            for (int e = 0; e < 8; ++e)
              acc = fmaf(aw[s8 * 8 + e], b2f((u16)v[e]), acc);
          }
          p.vb[(size_t)b * 1024 + j] = f2b(acc);
        }
      } else if (bid >= 64 && bid < 128) {
        const int grp = bid - 64;
        grouped_gemm8_pinned(hprev, wpin, red_s, sg_s);
        {
          int slot = tid;
          int b = slot >> 4, jj = slot & 15, j = grp * 16 + jj;
          p.gatesH[(size_t)b * G_ + j]        = sg_s[b * 64 + jj];
          p.gatesH[(size_t)b * G_ + 1024 + j] = sg_s[b * 64 + 16 + jj];
          p.gatesH[(size_t)b * G_ + 2048 + j] = sg_s[b * 64 + 32 + jj];
          p.gatesH[(size_t)b * G_ + 3072 + j] = sg_s[b * 64 + 48 + jj];
        }
      }
      gbar(p.bar, ++bargen);
      // ---- phase B: comb-v pinned (0..31) || batched logits h[t-8..t-1] (32..255, every 8th) ----
      if (bid < 32) {
        comb8_pinned(p, bid, t, wpin, red_s);
      } else if (batch) {
        const u16* Abase = p.hall + (size_t)(t - 8) * 32 * 1024;
        for (int task = (bid - 32) * 8 + (tid >> 6); task < 4000; task += 224 * 8) {
          int ct = task >> 3, mt = task & 7;
          wave_gemm<1>(Abase + (size_t)mt * 32 * 1024, p.wout, 1024, 0, ct * 64,
                       p.out_b, p.ring + (size_t)mt * 32 * V_, V_);
        }
      }
      gbar(p.bar, ++bargen);
      // ---- phase C: gates-x pinned + LSTM (128..191) || batch loss (192..255) ----
      if (bid >= 128 && bid < 192) {
        const int grp = bid - 128;
        grouped_gemm8_pinned(p.nbuf, wpin, red_s, sg_s);
        {
          int slot = tid;
          int b = slot >> 4, jj = slot & 15, j = grp * 16 + jj;
          float g0 = sg_s[b * 64 + jj]      + p.gatesH[(size_t)b * G_ + j]        + p.dec_b[j];
          float g1 = sg_s[b * 64 + 16 + jj] + p.gatesH[(size_t)b * G_ + 1024 + j] + p.dec_b[1024 + j];
          float g2 = sg_s[b * 64 + 32 + jj] + p.gatesH[(size_t)b * G_ + 2048 + j] + p.dec_b[2048 + j];
          float g3 = sg_s[b * 64 + 48 + jj] + p.gatesH[(size_t)b * G_ + 3072 + j] + p.dec_b[3072 + j];
          float ig = sigf(g0), fg = sigf(g1), gg = tanhf(g2), og = sigf(g3);
          float cn = fg * p.cbuf[b * 1024 + j] + ig * gg;
          float hn = og * tanhf(cn);
          p.cbuf[b * 1024 + j] = cn;
          u16 hb2 = f2b(hn);
          hnext[b * 1024 + j] = hb2;
          p.hall[((size_t)t * 32 + b) * 1024 + j] = hb2;
        }
      } else if (bid >= 192 && batch) {
        int base = (bid - 192) * 4;
        for (int rr = 0; rr < 4; ++rr) {
          int m = base + rr, gm = (t - 8) * 32 + m;
          loss_row_bf16<false>(p.ring + (size_t)m * V_, p.target[gm], &p.loss_p[gm],
                               nullptr, red_s);
        }
      }
      gbar(p.bar, ++bargen);
      pd ^= 1;
    }
    // ---- E1: batched logits for h[56..63] on all 256 blocks ----
    {
      const u16* Abase = p.hall + (size_t)56 * 32 * 1024;
      for (int task = bid * 8 + (tid >> 6); task < 4000; task += 2048) {
        int ct = task >> 3, mt = task & 7;
        wave_gemm<1>(Abase + (size_t)mt * 32 * 1024, p.wout, 1024, 0, ct * 64,
                     p.out_b, p.ring + (size_t)mt * 32 * V_, V_);
      }
    }
    gbar(p.bar, ++bargen);
    // ---- E2: loss rows 1792..2047 on blocks 0..127 ----
    if (bid < 128) {
      for (int rr = 0; rr < 2; ++rr) {
        int m = bid * 2 + rr, gm = 56 * 32 + m;
        loss_row_bf16<false>(p.ring + (size_t)m * V_, p.target[gm], &p.loss_p[gm],
                             nullptr, red_s);
      }
    }
    gbar(p.bar, ++bargen);
  } else {
    // ---- tf=0: per-step feedback path ----
    for (int t = 0; t < 64; ++t) {
      const u16* hprev = p.hbuf + (size_t)pd * B_ * H_;
      u16* hnext = p.hbuf + (size_t)(pd ^ 1) * B_ * H_;
      if (bid < 32) {
        float* xsh = red_s;
        float* hsh = red_s + 1024;
        float* ssc = red_s + 2048;
        float* aw  = red_s + 2560;
        const int b = bid;
        int tok = (t > 0) ? p.prevtok[b] : 0;
        {
          float2 v = *(const float2*)(p.dec_emb + (size_t)tok * 1024 + tid * 2);
          float x0 = fmaxf(v.x, 0.f), x1 = fmaxf(v.y, 0.f);
          xsh[tid * 2] = x0; xsh[tid * 2 + 1] = x1;
          *(ushort2*)(p.xb + (size_t)b * 1024 + tid * 2) = make_ushort2(f2b(x0), f2b(x1));
          ushort2 hq = *(const ushort2*)(hprev + (size_t)b * 1024 + tid * 2);
          hsh[tid * 2] = b2f(hq.x); hsh[tid * 2 + 1] = b2f(hq.y);
        }
        __syncthreads();
        {
          const int sidx = tid & 63, q = tid >> 6;
          const u16* wr = p.wattn + (size_t)sidx * 2048 + q * 256;
          const float* src = (q < 4) ? (xsh + q * 256) : (hsh + (q - 4) * 256);
          float acc = 0.f;
          for (int k8 = 0; k8 < 32; ++k8) {
            bf16x8 v = *(const bf16x8*)(wr + k8 * 8);
#pragma unroll
            for (int e = 0; e < 8; ++e)
              acc = fmaf(src[k8 * 8 + e], b2f((u16)v[e]), acc);
          }
          ssc[q * 64 + sidx] = acc;
        }
        __syncthreads();
        if (tid < 64) {
          float sc = p.attn_b[tid];
#pragma unroll
          for (int q = 0; q < 8; ++q) sc += ssc[q * 64 + tid];
          float m = sc;
#pragma unroll
          for (int off = 32; off; off >>= 1) m = fmaxf(m, __shfl_xor(m, off));
          float e = expf(sc - m), sum = e;
#pragma unroll
          for (int off = 32; off; off >>= 1) sum += __shfl_xor(sum, off);
          aw[tid] = e / sum;
        }
        __syncthreads();
        for (int j = tid; j < 1024; j += BT) {
          const u16* rowp = p.enc_bs + ((size_t)b * 1024 + j) * 64;
          float acc = 0.f;
#pragma unroll
          for (int s8 = 0; s8 < 8; ++s8) {
            bf16x8 v = *(const bf16x8*)(rowp + s8 * 8);
#pragma unroll
            for (int e = 0; e < 8; ++e)
              acc = fmaf(aw[s8 * 8 + e], b2f((u16)v[e]), acc);
          }
          p.vb[(size_t)b * 1024 + j] = f2b(acc);
        }
      } else if (bid >= 64 && bid < 128) {
        const int grp = bid - 64;
        grouped_gemm8(hprev, p.wdecG, 2048, 1024, grp, red_s, sg_s);
        {
          int slot = tid;
          int b = slot >> 4, jj = slot & 15, j = grp * 16 + jj;
          p.gatesH[(size_t)b * G_ + j]        = sg_s[b * 64 + jj];
          p.gatesH[(size_t)b * G_ + 1024 + j] = sg_s[b * 64 + 16 + jj];
          p.gatesH[(size_t)b * G_ + 2048 + j] = sg_s[b * 64 + 32 + jj];
          p.gatesH[(size_t)b * G_ + 3072 + j] = sg_s[b * 64 + 48 + jj];
        }
      }
      gbar(p.bar, ++bargen);
      if (bid < 32) comb8<2048, false>(p, bid, t, red_s);
      gbar(p.bar, ++bargen);
      if (bid < 64) {
        grouped_gemm8(p.nbuf, p.wdecG, 2048, 0, bid, red_s, sg_s);
        {
          int slot = tid;
          int b = slot >> 4, jj = slot & 15, j = bid * 16 + jj;
          float g0 = sg_s[b * 64 + jj]      + p.gatesH[(size_t)b * G_ + j]        + p.dec_b[j];
          float g1 = sg_s[b * 64 + 16 + jj] + p.gatesH[(size_t)b * G_ + 1024 + j] + p.dec_b[1024 + j];
          float g2 = sg_s[b * 64 + 32 + jj] + p.gatesH[(size_t)b * G_ + 2048 + j] + p.dec_b[2048 + j];
          float g3 = sg_s[b * 64 + 48 + jj] + p.gatesH[(size_t)b * G_ + 3072 + j] + p.dec_b[3072 + j];
          float ig = sigf(g0), fg = sigf(g1), gg = tanhf(g2), og = sigf(g3);
          float cn = fg * p.cbuf[b * 1024 + j] + ig * gg;
          float hn = og * tanhf(cn);
          p.cbuf[b * 1024 + j] = cn;
          u16 hb2 = f2b(hn);
          hnext[b * 1024 + j] = hb2;
          p.hall[((size_t)t * 32 + b) * 1024 + j] = hb2;
        }
      }
      gbar(p.bar, ++bargen);
      pd ^= 1;
      for (int task = gwid; task < 500; task += NWAVE)
        wave_gemm<1>(p.hbuf + (size_t)pd * B_ * H_, p.wout, 1024, 0, task * 64,
                     p.out_b, p.ring, V_);
      gbar(p.bar, ++bargen);
      if (bid < 32)
        loss_row_bf16<true>(p.ring + (size_t)bid * V_, p.target[t * 32 + bid],
                            &p.loss_p[t * 32 + bid], &p.prevtok[bid], red_s);
      gbar(p.bar, ++bargen);
    }
  }

  // ---------- final sum ----------
  if (bid == 0) {
    float a = 0.f;
    for (int i = tid; i < T_ * B_; i += BT) a += p.loss_p[i];
    red_s[tid] = a;
    __syncthreads();
    for (int off = 256; off; off >>= 1) {
      if (tid < off) red_s[tid] += red_s[tid + off];
      __syncthreads();
    }
    if (tid == 0) p.out[0] = red_s[0];
  }
}

// ---------------- host launch ----------------
extern "C" void kernel_launch(void* const* d_in, const int* in_sizes, int n_in,
                              void* d_out, int out_size, void* d_ws, size_t ws_size,
                              hipStream_t stream) {
  (void)in_sizes; (void)n_in; (void)out_size; (void)ws_size;
  Params p;
  p.input   = (const int*)d_in[0];
  p.target  = (const int*)d_in[1];
  p.use_tf  = (const int*)d_in[2];
  p.enc_emb = (const float*)d_in[3];
  p.enc_Wih = (const float*)d_in[4];
  p.enc_Whh = (const float*)d_in[5];
  p.enc_b   = (const float*)d_in[6];
  p.dec_emb = (const float*)d_in[7];
  p.dec_Wih = (const float*)d_in[8];
  p.dec_Whh = (const float*)d_in[9];
  p.dec_b   = (const float*)d_in[10];
  p.attn_W  = (const float*)d_in[11];
  p.attn_b  = (const float*)d_in[12];
  p.comb_W  = (const float*)d_in[13];
  p.comb_b  = (const float*)d_in[14];
  p.out_W   = (const float*)d_in[15];
  p.out_b   = (const float*)d_in[16];
  p.out     = (float*)d_out;

  char* ws = (char*)d_ws;
  size_t off = 0;
  auto alloc = [&](size_t bytes) {
    void* q = ws + off;
    off += ((bytes + 255) & ~(size_t)255);
    return q;
  };
  p.Xbf     = (u16*)alloc((size_t)S_ * B_ * H_ * 2);       // 4.2 MB
  p.encXbf  = (u16*)alloc((size_t)S_ * B_ * G_ * 2);       // 16.8 MB (ring aliases after encoder)
  p.enc_bs  = (u16*)alloc((size_t)B_ * H_ * S_ * 2);       // 4.2 MB
  p.hall    = (u16*)alloc((size_t)T_ * B_ * H_ * 2);       // 4.2 MB
  p.hbuf    = (u16*)alloc((size_t)2 * B_ * H_ * 2);
  p.xb      = (u16*)alloc((size_t)B_ * H_ * 2);
  p.vb      = (u16*)alloc((size_t)B_ * H_ * 2);
  p.nbuf    = (u16*)alloc((size_t)B_ * H_ * 2);
  p.xball   = (u16*)alloc((size_t)T_ * B_ * H_ * 2);       // 4.2 MB
  p.combX   = (float*)alloc((size_t)T_ * B_ * H_ * 4);     // 8.4 MB
  p.scoreX  = (float*)alloc((size_t)T_ * B_ * 64 * 4);     // 0.5 MB
  p.gatesH  = (float*)alloc((size_t)B_ * G_ * 4);          // 0.5 MB
  p.cbuf    = (float*)alloc((size_t)B_ * H_ * 4);
  p.loss_p  = (float*)alloc((size_t)T_ * B_ * 4);
  p.prevtok = (int*)alloc(B_ * 4);
  p.bar     = (unsigned*)alloc(1024);
  p.wencWih = (u16*)alloc((size_t)G_ * H_ * 2);            // 8.4 MB
  p.wencWhh = (u16*)alloc((size_t)G_ * H_ * 2);            // 8.4 MB
  p.wdecG   = (u16*)alloc((size_t)G_ * 2 * H_ * 2);        // 16.8 MB
  p.wcomb   = (u16*)alloc((size_t)H_ * 2 * H_ * 2);        // 4.2 MB
  p.wattn   = (u16*)alloc((size_t)S_ * 2 * H_ * 2);        // 0.26 MB
  p.wout    = (u16*)alloc((size_t)V_ * H_ * 2);            // 65.5 MB
  // logits ring: 256 rows x 32000 bf16 = 16.38 MB, aliases dead-after-encoder encXbf
  p.ring = p.encXbf;
  // total ~147 MB

  binit<<<1, 288, 0, stream>>>(p.bar);
  seq2seq_all<<<NB, BT, 0, stream>>>(p);
}